// Round 5
// baseline (1080.824 us; speedup 1.0000x reference)
//
#include <hip/hip_runtime.h>
#include <hip/hip_bf16.h>

#define NB 16
#define NP 4096
#define MS 1024
#define NN 65536
#define FIN 64
#define FOUT 128
#define KNN_MARGIN 0.25f

typedef __attribute__((ext_vector_type(8))) short short8;
typedef __attribute__((ext_vector_type(4))) float f32x4;

// DPP cumulative-max step on a (dist,idx) key, using v_max_f64.
// Keys are positive f64 bit patterns (finite f32 dist in high word => never NaN),
// so IEEE fmax == unsigned 64-bit max. Invalid DPP lanes -> 0.0 (identity).
// NOTE direction: row_shr:N moves lane L-N -> lane L, so cumulative max
// accumulates UPWARD (harvest at the TOP lane of the group, not lane 0).
template <int CTRL>
__device__ __forceinline__ unsigned long long dpp_fmax_step(unsigned long long k) {
    unsigned lo = (unsigned)k, hi = (unsigned)(k >> 32);
    unsigned plo = (unsigned)__builtin_amdgcn_update_dpp(0, (int)lo, CTRL, 0xf, 0xf, true);
    unsigned phi = (unsigned)__builtin_amdgcn_update_dpp(0, (int)hi, CTRL, 0xf, 0xf, true);
    unsigned long long pk = ((unsigned long long)phi << 32) | plo;
    double a = __builtin_bit_cast(double, k);
    double p = __builtin_bit_cast(double, pk);
    return __builtin_bit_cast(unsigned long long, fmax(a, p));
}

__device__ __forceinline__ unsigned short bf16_rn(float v) {
    unsigned u = __float_as_uint(v);
    unsigned r = u + 0x7FFF + ((u >> 16) & 1);
    return (unsigned short)(r >> 16);
}

// ---------------------------------------------------------------- front: FPS + GEMM + xnorm/split fused
__global__ __launch_bounds__(512, 1) void front_kernel(
        const float* __restrict__ pos, const float* __restrict__ feat,
        const float* __restrict__ W, const float* __restrict__ bias,
        int* __restrict__ fps_idx, float* __restrict__ out_pos, float* __restrict__ out_batch,
        float* __restrict__ xnorm, unsigned short* __restrict__ Xhi, unsigned short* __restrict__ Xlo,
        __hip_bfloat16* __restrict__ hout, float* __restrict__ gsum, float* __restrict__ gsq) {
    // FPS view: plds4[4096] float4 (65536 B) + idxL[1024] int (4096 B) + wk[2][8] double (128 B)
    // GEMM view: first 52224 B as floats (wt/fl)
    __shared__ __align__(16) char smraw[69760];
    const int t = threadIdx.x;
    const int b = blockIdx.x;
    if (b < 16) {
        // ---------------- FPS: 512 threads x 8 pts/thread
        // Combine: per-wave key write -> barrier -> lane-indexed single b64 read +
        // 3-step DPP f64-max reduce (result lands in lane 7) + readlane(7).
        float4* plds4 = (float4*)smraw;
        float*  plin  = (float*)smraw;                    // linear staging view
        int* idxL = (int*)(smraw + 65536);
        double* wk = (double*)(smraw + 65536 + 4096);     // [2][8] per-wave keys
        const float* pb = pos + (size_t)b * NP * 3;
#pragma unroll
        for (int i = 0; i < 24; i++) { int id = t + 512 * i; plin[id] = pb[id]; }
        __syncthreads();
        float px[8], py[8], pz[8], dist[8];
#pragma unroll
        for (int i = 0; i < 8; i++) {
            int p = t + 512 * i;
            px[i] = plin[p * 3 + 0]; py[i] = plin[p * 3 + 1]; pz[i] = plin[p * 3 + 2];
            dist[i] = INFINITY;
        }
        __syncthreads();   // all linear reads done before float4 overwrite
#pragma unroll
        for (int i = 0; i < 8; i++) {
            int p = t + 512 * i;
            plds4[p] = (float4){px[i], py[i], pz[i], 0.f};
        }
        if (t == 0) idxL[0] = 0;
        __syncthreads();
        float4 c0 = plds4[0];
        float lx = c0.x, ly = c0.y, lz = c0.z;
        const int ln = t & 63, wv = t >> 6;   // 8 waves
        const int rd7 = ln & 7;               // which wave's key this lane reads
        for (int m = 1; m < MS; m++) {
#pragma unroll
            for (int i = 0; i < 8; i++) {
                float dx = px[i] - lx, dy = py[i] - ly, dz = pz[i] - lz;
                float d = dx * dx + dy * dy + dz * dz;
                dist[i] = fminf(dist[i], d);
            }
            float d1[4]; int i1[4];
#pragma unroll
            for (int i = 0; i < 4; i++) {
                bool g = dist[i + 4] > dist[i];
                d1[i] = g ? dist[i + 4] : dist[i]; i1[i] = g ? (i + 4) : i;
            }
            float d2[2]; int i2[2];
#pragma unroll
            for (int i = 0; i < 2; i++) {
                bool g = d1[i + 2] > d1[i];
                d2[i] = g ? d1[i + 2] : d1[i]; i2[i] = g ? i1[i + 2] : i1[i];
            }
            bool g3 = d2[1] > d2[0];
            float bd = g3 ? d2[1] : d2[0];
            int bi = g3 ? i2[1] : i2[0];
            int bp = t + (bi << 9);
            unsigned long long key =
                ((unsigned long long)__float_as_uint(bd) << 32) | (unsigned)(~bp);
            key = dpp_fmax_step<0x111>(key);   // row_shr:1
            key = dpp_fmax_step<0x112>(key);   // row_shr:2
            key = dpp_fmax_step<0x114>(key);   // row_shr:4
            key = dpp_fmax_step<0x118>(key);   // row_shr:8
            key = dpp_fmax_step<0x142>(key);   // row_bcast15
            key = dpp_fmax_step<0x143>(key);   // row_bcast31
            const int par = (m & 1) * 8;
            if (ln == 63) wk[par + wv] = __builtin_bit_cast(double, key);
            __syncthreads();
            // lane-indexed read: lane L holds key of wave L&7 (one b64 per wave)
            double kx = wk[par + rd7];
            unsigned long long kk = __builtin_bit_cast(unsigned long long, kx);
            kk = dpp_fmax_step<0x111>(kk);     // 8-lane group reduce: shr1
            kk = dpp_fmax_step<0x112>(kk);     // shr2
            kk = dpp_fmax_step<0x114>(kk);     // shr4 -> lane 7 has global max
            int lw = __builtin_amdgcn_readlane((int)(unsigned)kk, 7);
            int bpw = (int)(~(unsigned)lw) & 0xFFF;
            float4 c = plds4[bpw];             // one b128 broadcast read
            lx = c.x; ly = c.y; lz = c.z;
            if (t == 0) idxL[m] = bpw;
        }
        __syncthreads();
        for (int m = t; m < MS; m += 512) {
            int ix = idxL[m];
            size_t o = (size_t)b * MS + m;
            fps_idx[o] = ix;
            float4 c = plds4[ix];
            out_pos[o * 3 + 0] = c.x;
            out_pos[o * 3 + 1] = c.y;
            out_pos[o * 3 + 2] = c.z;
            out_batch[o] = (float)b;
        }
    } else if (b < 272) {
        // ---------------- GEMM + BN stats (rows (b-16)*256 .. +255), 512 threads
        float* wt = (float*)smraw;            // [128][68] W^T
        float* fl = (float*)smraw + 8704;     // [64][68] feature tile
#pragma unroll
        for (int it = 0; it < 4; it++) {
            int lid = t + 512 * it;
            int k = lid >> 5, c4 = lid & 31;
            float4 v = *(const float4*)&W[k * FOUT + c4 * 4];
            wt[(c4 * 4 + 0) * 68 + k] = v.x;
            wt[(c4 * 4 + 1) * 68 + k] = v.y;
            wt[(c4 * 4 + 2) * 68 + k] = v.z;
            wt[(c4 * 4 + 3) * 68 + k] = v.w;
        }
        const int rowbase0 = (b - 16) * 256;
        const int rg = t >> 5, cg = t & 31;
        float sums[4] = {0, 0, 0, 0};
        float sqs[4]  = {0, 0, 0, 0};
        for (int sub = 0; sub < 4; sub++) {
            const int rowbase = rowbase0 + sub * 64;
            __syncthreads();
#pragma unroll
            for (int it = 0; it < 2; it++) {
                int lid = t + 512 * it;
                int r = lid >> 4, f4 = lid & 15;
                float4 v = *(const float4*)&feat[(size_t)(rowbase + r) * FIN + f4 * 4];
                *(float4*)&fl[r * 68 + f4 * 4] = v;
            }
            __syncthreads();
            float acc[4][4];
#pragma unroll
            for (int i = 0; i < 4; i++)
#pragma unroll
                for (int j = 0; j < 4; j++) acc[i][j] = 0.f;
#pragma unroll 2
            for (int k4 = 0; k4 < 16; k4++) {
                float4 f4v[4], w4v[4];
#pragma unroll
                for (int i = 0; i < 4; i++) f4v[i] = *(float4*)&fl[(rg * 4 + i) * 68 + k4 * 4];
#pragma unroll
                for (int j = 0; j < 4; j++) w4v[j] = *(float4*)&wt[(cg + 32 * j) * 68 + k4 * 4];
#pragma unroll
                for (int i = 0; i < 4; i++)
#pragma unroll
                    for (int j = 0; j < 4; j++) {
                        acc[i][j] = fmaf(f4v[i].x, w4v[j].x, acc[i][j]);
                        acc[i][j] = fmaf(f4v[i].y, w4v[j].y, acc[i][j]);
                        acc[i][j] = fmaf(f4v[i].z, w4v[j].z, acc[i][j]);
                        acc[i][j] = fmaf(f4v[i].w, w4v[j].w, acc[i][j]);
                    }
            }
#pragma unroll
            for (int j = 0; j < 4; j++) {
                int c = cg + 32 * j;
                float bc = bias[c];
#pragma unroll
                for (int i = 0; i < 4; i++) {
                    float h = acc[i][j] + bc;
                    sums[j] += h; sqs[j] += h * h;
                    hout[(size_t)(rowbase + rg * 4 + i) * FOUT + c] = __float2bfloat16(h);
                }
            }
        }
        __syncthreads();
        float* suml = fl;
        float* sql  = wt;
#pragma unroll
        for (int j = 0; j < 4; j++) {
            suml[rg * FOUT + cg + 32 * j] = sums[j];
            sql[rg * FOUT + cg + 32 * j]  = sqs[j];
        }
        __syncthreads();
        if (t < FOUT) {
            float S = 0.f, Q = 0.f;
#pragma unroll
            for (int r = 0; r < 16; r++) { S += suml[r * FOUT + t]; Q += sql[r * FOUT + t]; }
            atomicAdd(&gsum[t], S);
            atomicAdd(&gsq[t], Q);
        }
    } else {
        // ---------------- xnorm + bf16 hi/lo split (512 threads, 128 blocks)
        int r = (b - 272) * 512 + t;
        const float4* fr = (const float4*)&feat[(size_t)r * FIN];
        unsigned short hrow[64], lrow[64];
        float s = 0.f;
#pragma unroll
        for (int i = 0; i < 16; i++) {
            float4 v = fr[i];
            s += v.x * v.x + v.y * v.y + v.z * v.z + v.w * v.w;
            float vv[4] = {v.x, v.y, v.z, v.w};
#pragma unroll
            for (int j = 0; j < 4; j++) {
                unsigned short h = bf16_rn(vv[j]);
                float hf = __uint_as_float((unsigned)h << 16);
                hrow[4 * i + j] = h;
                lrow[4 * i + j] = bf16_rn(vv[j] - hf);
            }
        }
        xnorm[r] = s;
#pragma unroll
        for (int i = 0; i < 8; i++) {
            short8 hv, lv;
#pragma unroll
            for (int j = 0; j < 8; j++) { hv[j] = (short)hrow[8 * i + j]; lv[j] = (short)lrow[8 * i + j]; }
            *(short8*)&Xhi[(size_t)r * 64 + 8 * i] = hv;
            *(short8*)&Xlo[(size_t)r * 64 + 8 * i] = lv;
        }
    }
}

// ---------------------------------------------------------------- BN finalize
__global__ void finalize_kernel(const float* __restrict__ gsum, const float* __restrict__ gsq,
        const float* __restrict__ gamma, const float* __restrict__ beta,
        float* __restrict__ acoef, float* __restrict__ ccoef) {
    int c = threadIdx.x;
    float mean = gsum[c] * (1.0f / NN);
    float var  = gsq[c] * (1.0f / NN) - mean * mean;
    float s = rsqrtf(var + 1e-5f) * gamma[c];
    acoef[c] = s;
    ccoef[c] = beta[c] - mean * s;
}

// ---------------------------------------------------------------- KNN filter: MFMA + two-phase threshold
// grid 512: cloud(16) x qgroup(16) x half(2). Wave w owns queries qg*64+w*16..+15 vs 2048 points.
// Phase 1: per (lane,r) stream of 128 points keep 2 smallest scores (unconditional min pair).
// T[q] = 16th smallest of the 32 collected values (32 distinct points => exact d16 <= T).
// Phase 2: re-stream, emit point idx where s <= T+margin into per-query LDS buffer (atomic).
// Margin >> 2x bf16-3pass error => exact-metric top-16 always emitted; refine re-ranks in fp32.
__global__ __launch_bounds__(256, 2) void knn_kernel(
        const unsigned short* __restrict__ Xhi, const unsigned short* __restrict__ Xlo,
        const int* __restrict__ fps_idx, const float* __restrict__ xnorm,
        unsigned short* __restrict__ cand) {
    __shared__ float TL[4][16][32];            // [wave][q][col*2+{0,1}] collected values
    __shared__ float TQ[4][16];                // per-query threshold
    __shared__ int   cntL[4][16];
    __shared__ unsigned short buf[4][16][64];
    const int t = threadIdx.x, b = blockIdx.x;
    const int cloud = b & 15, qg = (b >> 4) & 15, half = b >> 8;
    const int wave = t >> 6, lane = t & 63;
    const int quad = lane >> 4, col = lane & 15;
    const int cbase = cloud * NP;
    const int qloc = qg * 64 + wave * 16;

    // A fragments (loop-invariant): A[m=lane&15][k=quad*8+j]
    const int qrow = fps_idx[cloud * MS + qloc + col];
    const unsigned short* Qh = Xhi + (size_t)(cbase + qrow) * 64;
    const unsigned short* Ql = Xlo + (size_t)(cbase + qrow) * 64;
    short8 Ah0 = *(const short8*)(Qh + quad * 8);
    short8 Ah1 = *(const short8*)(Qh + 32 + quad * 8);
    short8 Al0 = *(const short8*)(Ql + quad * 8);
    short8 Al1 = *(const short8*)(Ql + 32 + quad * 8);

    const int pstart = half * 2048;
    // -------- phase 1: unconditional 2-smallest per (lane, r) stream
    float mA[4] = {INFINITY, INFINITY, INFINITY, INFINITY};
    float mB[4] = {INFINITY, INFINITY, INFINITY, INFINITY};
    for (int tile = 0; tile < 128; tile++) {
        const int prow = cbase + pstart + tile * 16 + col;
        const unsigned short* Bh = Xhi + (size_t)prow * 64;
        const unsigned short* Bl = Xlo + (size_t)prow * 64;
        short8 bh0 = *(const short8*)(Bh + quad * 8);
        short8 bh1 = *(const short8*)(Bh + 32 + quad * 8);
        short8 bl0 = *(const short8*)(Bl + quad * 8);
        short8 bl1 = *(const short8*)(Bl + 32 + quad * 8);
        f32x4 acc = {0.f, 0.f, 0.f, 0.f};
        acc = __builtin_amdgcn_mfma_f32_16x16x32_bf16(Ah0, bh0, acc, 0, 0, 0);
        acc = __builtin_amdgcn_mfma_f32_16x16x32_bf16(Ah1, bh1, acc, 0, 0, 0);
        acc = __builtin_amdgcn_mfma_f32_16x16x32_bf16(Al0, bh0, acc, 0, 0, 0);
        acc = __builtin_amdgcn_mfma_f32_16x16x32_bf16(Al1, bh1, acc, 0, 0, 0);
        acc = __builtin_amdgcn_mfma_f32_16x16x32_bf16(Ah0, bl0, acc, 0, 0, 0);
        acc = __builtin_amdgcn_mfma_f32_16x16x32_bf16(Ah1, bl1, acc, 0, 0, 0);
        float xnv = xnorm[prow];
        // C layout (validated R6/R7): score for query quad*4+r at point pstart+tile*16+col
#pragma unroll
        for (int r = 0; r < 4; r++) {
            float s = fmaf(-2.0f, acc[r], xnv);
            float mx = fmaxf(mA[r], s);
            mA[r] = fminf(mA[r], s);
            mB[r] = fminf(mB[r], mx);
        }
    }
    // -------- threshold: T[q] = 16th smallest of {mA,mB over 16 cols} (wave-local LDS, no barrier)
#pragma unroll
    for (int r = 0; r < 4; r++) {
        TL[wave][quad * 4 + r][col * 2 + 0] = mA[r];
        TL[wave][quad * 4 + r][col * 2 + 1] = mB[r];
    }
    if (lane < 16) cntL[wave][lane] = 0;
    {
        const int q = lane >> 2, j0 = (lane & 3) * 8;
        float v[32];
#pragma unroll
        for (int j = 0; j < 32; j++) v[j] = TL[wave][q][j];
#pragma unroll
        for (int u = 0; u < 8; u++) {
            float vj = TL[wave][q][j0 + u];
            int jj = j0 + u, rank = 0;
#pragma unroll
            for (int k = 0; k < 32; k++)
                rank += (v[k] < vj || (v[k] == vj && k < jj)) ? 1 : 0;
            if (rank == 15) TQ[wave][q] = vj;
        }
    }
    // -------- phase 2: emit candidates below threshold
    float T0 = TQ[wave][quad * 4 + 0] + KNN_MARGIN;
    float T1 = TQ[wave][quad * 4 + 1] + KNN_MARGIN;
    float T2 = TQ[wave][quad * 4 + 2] + KNN_MARGIN;
    float T3 = TQ[wave][quad * 4 + 3] + KNN_MARGIN;
    for (int tile = 0; tile < 128; tile++) {
        const int pidx = pstart + tile * 16 + col;
        const int prow = cbase + pidx;
        const unsigned short* Bh = Xhi + (size_t)prow * 64;
        const unsigned short* Bl = Xlo + (size_t)prow * 64;
        short8 bh0 = *(const short8*)(Bh + quad * 8);
        short8 bh1 = *(const short8*)(Bh + 32 + quad * 8);
        short8 bl0 = *(const short8*)(Bl + quad * 8);
        short8 bl1 = *(const short8*)(Bl + 32 + quad * 8);
        f32x4 acc = {0.f, 0.f, 0.f, 0.f};
        acc = __builtin_amdgcn_mfma_f32_16x16x32_bf16(Ah0, bh0, acc, 0, 0, 0);
        acc = __builtin_amdgcn_mfma_f32_16x16x32_bf16(Ah1, bh1, acc, 0, 0, 0);
        acc = __builtin_amdgcn_mfma_f32_16x16x32_bf16(Al0, bh0, acc, 0, 0, 0);
        acc = __builtin_amdgcn_mfma_f32_16x16x32_bf16(Al1, bh1, acc, 0, 0, 0);
        acc = __builtin_amdgcn_mfma_f32_16x16x32_bf16(Ah0, bl0, acc, 0, 0, 0);
        acc = __builtin_amdgcn_mfma_f32_16x16x32_bf16(Ah1, bl1, acc, 0, 0, 0);
        float xnv = xnorm[prow];
        float s0 = fmaf(-2.0f, acc[0], xnv);
        float s1 = fmaf(-2.0f, acc[1], xnv);
        float s2 = fmaf(-2.0f, acc[2], xnv);
        float s3 = fmaf(-2.0f, acc[3], xnv);
        if (s0 <= T0) { int p = atomicAdd(&cntL[wave][quad * 4 + 0], 1); if (p < 64) buf[wave][quad * 4 + 0][p] = (unsigned short)pidx; }
        if (s1 <= T1) { int p = atomicAdd(&cntL[wave][quad * 4 + 1], 1); if (p < 64) buf[wave][quad * 4 + 1][p] = (unsigned short)pidx; }
        if (s2 <= T2) { int p = atomicAdd(&cntL[wave][quad * 4 + 2], 1); if (p < 64) buf[wave][quad * 4 + 2][p] = (unsigned short)pidx; }
        if (s3 <= T3) { int p = atomicAdd(&cntL[wave][quad * 4 + 3], 1); if (p < 64) buf[wave][quad * 4 + 3][p] = (unsigned short)pidx; }
    }
    // -------- dump (coalesced 128B per query; sentinel-pad)
#pragma unroll
    for (int q = 0; q < 16; q++) {
        int n = cntL[wave][q];
        unsigned short val = (lane < n) ? buf[wave][q][lane] : (unsigned short)0xFFFF;
        cand[(size_t)(cloud * MS + qloc + q) * 128 + half * 64 + lane] = val;
    }
}

// ---------------------------------------------------------------- refine: exact fp32 top-16 + gather/BN/ReLU/maxpool
// block = one query; 128 candidate slots (sentinel-padded), 2 lanes/candidate.
__global__ __launch_bounds__(256) void refine_kernel(
        const float* __restrict__ feat, const int* __restrict__ fps_idx,
        const float* __restrict__ xnorm, const unsigned short* __restrict__ cand,
        const __hip_bfloat16* __restrict__ h, const float* __restrict__ acoef,
        const float* __restrict__ ccoef, float* __restrict__ out_feat) {
    __shared__ float qlds[64];
    __shared__ float cD[128];
    __shared__ int   cI[128];
    __shared__ int   fIdx[16];
    __shared__ float cf[256];
    const int t = threadIdx.x, b = blockIdx.x;
    const int cloud = b & 15, m = b >> 4;          // cloud <-> XCD locality
    const int q = cloud * MS + m;
    const int cbase = cloud * NP;
    if (t < 128) cf[t] = acoef[t]; else cf[t] = ccoef[t - 128];
    if (t < 16) {
        int qr = fps_idx[q];
        float4 v = ((const float4*)(feat + (size_t)(cbase + qr) * FIN))[t];
        *(float4*)&qlds[t * 4] = v;
    }
    __syncthreads();
    // exact fp32 distance: candidate c = t>>1, half jh = t&1 covers 32 dims
    const int c = t >> 1, jh = t & 1;
    const unsigned short cs = cand[(size_t)q * 128 + c];
    const bool valid = (cs != 0xFFFF);
    const int cidx = valid ? (int)cs : 0;
    const float4* xr = (const float4*)(feat + (size_t)(cbase + cidx) * FIN) + jh * 8;
    float a0 = 0.f, a1 = 0.f, a2 = 0.f, a3 = 0.f;
#pragma unroll
    for (int i = 0; i < 8; i++) {
        float4 x4 = xr[i];
        a0 = fmaf(qlds[jh * 32 + 4 * i + 0], x4.x, a0);
        a1 = fmaf(qlds[jh * 32 + 4 * i + 1], x4.y, a1);
        a2 = fmaf(qlds[jh * 32 + 4 * i + 2], x4.z, a2);
        a3 = fmaf(qlds[jh * 32 + 4 * i + 3], x4.w, a3);
    }
    float a = (a0 + a1) + (a2 + a3);
    a += __shfl_xor(a, 1);
    if (jh == 0) {
        cD[c] = valid ? fmaf(-2.0f, a, xnorm[cbase + cidx]) : INFINITY;
        cI[c] = valid ? cidx : (65536 + c);   // distinct tiebreak ids for sentinels
    }
    __syncthreads();
    // rank-count among 128 (lex (d, idx); >=32 real distinct candidates guaranteed)
    if (t < 128) {
        float dv = cD[t]; int iv = cI[t]; int rank = 0;
#pragma unroll 8
        for (int j = 0; j < 128; j++) {
            float dj = cD[j]; int ij = cI[j];
            rank += (dj < dv || (dj == dv && ij < iv)) ? 1 : 0;
        }
        if (rank < 16) fIdx[rank] = iv;
    }
    __syncthreads();
    // gather + BN affine + relu + maxpool
    if (t < 128) {
        const __hip_bfloat16* hb = h + (size_t)cbase * FOUT;
        const float ac = cf[t], cc = cf[128 + t];
        float mx = -INFINITY;
#pragma unroll
        for (int k = 0; k < 16; k++) {
            int row = fIdx[k];
            float hv = __bfloat162float(hb[(size_t)row * FOUT + t]);
            mx = fmaxf(mx, fmaxf(fmaf(ac, hv, cc), 0.f));
        }
        out_feat[(size_t)q * FOUT + t] = mx;
    }
}

// ---------------------------------------------------------------- launch
extern "C" void kernel_launch(void* const* d_in, const int* in_sizes, int n_in,
                              void* d_out, int out_size, void* d_ws, size_t ws_size,
                              hipStream_t stream) {
    (void)in_sizes; (void)n_in; (void)out_size; (void)ws_size;
    const float* position = (const float*)d_in[0];
    const float* features = (const float*)d_in[1];
    const float* W        = (const float*)d_in[3];
    const float* bias     = (const float*)d_in[4];
    const float* gamma    = (const float*)d_in[5];
    const float* beta     = (const float*)d_in[6];
    float* out = (float*)d_out;

    char* ws = (char*)d_ws;
    int*   fps_idx = (int*)ws;                               // 64 KB
    float* gsum    = (float*)(ws + 65536);                   // 512 B
    float* gsq     = (float*)(ws + 66048);                   // 512 B
    float* acoef   = (float*)(ws + 66560);                   // 512 B
    float* ccoef   = (float*)(ws + 67072);                   // 512 B
    float* xnorm   = (float*)(ws + 67584);                   // 256 KB -> ends 329728
    unsigned short* cand = (unsigned short*)(ws + 329728);   // 4 MB   -> ends 4524032
    unsigned short* Xhi  = (unsigned short*)(ws + 4524032);  // 8 MB   -> ends 12912640
    __hip_bfloat16* hbuf = (__hip_bfloat16*)(ws + 12912640); // 16 MB  -> ends ~29.7 MB

    float* out_feat  = out;                 // [16384][128]
    float* out_pos   = out + 2097152;       // [16384][3]
    float* out_batch = out + 2146304;       // [16384]
    // Stash Xlo in the out_feat region (8 MB exact fit); refine overwrites it afterwards.
    unsigned short* Xlo = (unsigned short*)out;

    hipMemsetAsync(gsum, 0, 1024, stream);  // zero gsum+gsq
    front_kernel<<<400, 512, 0, stream>>>(position, features, W, bias,
                                          fps_idx, out_pos, out_batch, xnorm, Xhi, Xlo,
                                          hbuf, gsum, gsq);
    finalize_kernel<<<1, FOUT, 0, stream>>>(gsum, gsq, gamma, beta, acoef, ccoef);
    knn_kernel<<<512, 256, 0, stream>>>(Xhi, Xlo, fps_idx, xnorm, cand);
    refine_kernel<<<16384, 256, 0, stream>>>(features, fps_idx, xnorm, cand,
                                             hbuf, acoef, ccoef, out_feat);
}

// Round 6
// 988.463 us; speedup vs baseline: 1.0934x; 1.0934x over previous
//
#include <hip/hip_runtime.h>
#include <hip/hip_bf16.h>

#define NB 16
#define NP 4096
#define MS 1024
#define NN 65536
#define FIN 64
#define FOUT 128
#define KNN_MARGIN 0.25f

typedef __attribute__((ext_vector_type(8))) short short8;
typedef __attribute__((ext_vector_type(4))) float f32x4;

// DPP cumulative-max step on a (dist,idx) key, using v_max_f64.
// Keys are positive f64 bit patterns (finite f32 dist in high word => never NaN),
// so IEEE fmax == unsigned 64-bit max. Invalid DPP lanes -> 0.0 (identity).
template <int CTRL>
__device__ __forceinline__ unsigned long long dpp_fmax_step(unsigned long long k) {
    unsigned lo = (unsigned)k, hi = (unsigned)(k >> 32);
    unsigned plo = (unsigned)__builtin_amdgcn_update_dpp(0, (int)lo, CTRL, 0xf, 0xf, true);
    unsigned phi = (unsigned)__builtin_amdgcn_update_dpp(0, (int)hi, CTRL, 0xf, 0xf, true);
    unsigned long long pk = ((unsigned long long)phi << 32) | plo;
    double a = __builtin_bit_cast(double, k);
    double p = __builtin_bit_cast(double, pk);
    return __builtin_bit_cast(unsigned long long, fmax(a, p));
}

__device__ __forceinline__ unsigned short bf16_rn(float v) {
    unsigned u = __float_as_uint(v);
    unsigned r = u + 0x7FFF + ((u >> 16) & 1);
    return (unsigned short)(r >> 16);
}

// ---------------------------------------------------------------- front: FPS + GEMM + xnorm/split fused
__global__ __launch_bounds__(512, 1) void front_kernel(
        const float* __restrict__ pos, const float* __restrict__ feat,
        const float* __restrict__ W, const float* __restrict__ bias,
        int* __restrict__ fps_idx, float* __restrict__ out_pos, float* __restrict__ out_batch,
        float* __restrict__ xnorm, unsigned short* __restrict__ Xhi, unsigned short* __restrict__ Xlo,
        __hip_bfloat16* __restrict__ hout, float* __restrict__ gsum, float* __restrict__ gsq) {
    // FPS view: plds4[4096] float4 (65536 B) + idxL[1024] int (4096 B) + wk[2][8] double (128 B)
    // GEMM view: first 52224 B as floats (wt/fl)
    __shared__ __align__(16) char smraw[69760];
    const int t = threadIdx.x;
    const int b = blockIdx.x;
    if (b < 16) {
        // ---------------- FPS: 512 threads x 8 pts/thread; f64-max keys (R2-proven combine)
        float4* plds4 = (float4*)smraw;
        float*  plin  = (float*)smraw;                    // linear staging view
        int* idxL = (int*)(smraw + 65536);
        double* wk = (double*)(smraw + 65536 + 4096);     // [2][8] per-wave keys
        const float* pb = pos + (size_t)b * NP * 3;
#pragma unroll
        for (int i = 0; i < 24; i++) { int id = t + 512 * i; plin[id] = pb[id]; }
        __syncthreads();
        float px[8], py[8], pz[8], dist[8];
#pragma unroll
        for (int i = 0; i < 8; i++) {
            int p = t + 512 * i;
            px[i] = plin[p * 3 + 0]; py[i] = plin[p * 3 + 1]; pz[i] = plin[p * 3 + 2];
            dist[i] = INFINITY;
        }
        __syncthreads();   // all linear reads done before float4 overwrite
#pragma unroll
        for (int i = 0; i < 8; i++) {
            int p = t + 512 * i;
            plds4[p] = (float4){px[i], py[i], pz[i], 0.f};
        }
        if (t == 0) idxL[0] = 0;
        __syncthreads();
        float4 c0 = plds4[0];
        float lx = c0.x, ly = c0.y, lz = c0.z;
        const int ln = t & 63, wv = t >> 6;   // 8 waves
        for (int m = 1; m < MS; m++) {
#pragma unroll
            for (int i = 0; i < 8; i++) {
                float dx = px[i] - lx, dy = py[i] - ly, dz = pz[i] - lz;
                float d = dx * dx + dy * dy + dz * dz;
                dist[i] = fminf(dist[i], d);
            }
            float d1[4]; int i1[4];
#pragma unroll
            for (int i = 0; i < 4; i++) {
                bool g = dist[i + 4] > dist[i];
                d1[i] = g ? dist[i + 4] : dist[i]; i1[i] = g ? (i + 4) : i;
            }
            float d2[2]; int i2[2];
#pragma unroll
            for (int i = 0; i < 2; i++) {
                bool g = d1[i + 2] > d1[i];
                d2[i] = g ? d1[i + 2] : d1[i]; i2[i] = g ? i1[i + 2] : i1[i];
            }
            bool g3 = d2[1] > d2[0];
            float bd = g3 ? d2[1] : d2[0];
            int bi = g3 ? i2[1] : i2[0];
            int bp = t + (bi << 9);
            unsigned long long key =
                ((unsigned long long)__float_as_uint(bd) << 32) | (unsigned)(~bp);
            key = dpp_fmax_step<0x111>(key);   // row_shr:1
            key = dpp_fmax_step<0x112>(key);   // row_shr:2
            key = dpp_fmax_step<0x114>(key);   // row_shr:4
            key = dpp_fmax_step<0x118>(key);   // row_shr:8
            key = dpp_fmax_step<0x142>(key);   // row_bcast15
            key = dpp_fmax_step<0x143>(key);   // row_bcast31
            const int par = (m & 1) * 8;
            if (ln == 63) wk[par + wv] = __builtin_bit_cast(double, key);
            __syncthreads();
            double k0 = wk[par + 0], k1 = wk[par + 1];
            double k2 = wk[par + 2], k3 = wk[par + 3];
            double k4 = wk[par + 4], k5 = wk[par + 5];
            double k6 = wk[par + 6], k7 = wk[par + 7];
            double ka = fmax(k0, k1), kb = fmax(k2, k3);
            double kc = fmax(k4, k5), kd = fmax(k6, k7);
            ka = fmax(ka, kb);
            kc = fmax(kc, kd);
            unsigned long long kw = __builtin_bit_cast(unsigned long long, fmax(ka, kc));
            bp = (int)(~(unsigned)kw) & 0xFFF;
            float4 c = plds4[bp];                          // one b128 coords read
            lx = c.x; ly = c.y; lz = c.z;
            if (t == 0) idxL[m] = bp;
        }
        __syncthreads();
        for (int m = t; m < MS; m += 512) {
            int ix = idxL[m];
            size_t o = (size_t)b * MS + m;
            fps_idx[o] = ix;
            float4 c = plds4[ix];
            out_pos[o * 3 + 0] = c.x;
            out_pos[o * 3 + 1] = c.y;
            out_pos[o * 3 + 2] = c.z;
            out_batch[o] = (float)b;
        }
    } else if (b < 272) {
        // ---------------- GEMM + BN stats (rows (b-16)*256 .. +255), 512 threads
        float* wt = (float*)smraw;            // [128][68] W^T
        float* fl = (float*)smraw + 8704;     // [64][68] feature tile
#pragma unroll
        for (int it = 0; it < 4; it++) {
            int lid = t + 512 * it;
            int k = lid >> 5, c4 = lid & 31;
            float4 v = *(const float4*)&W[k * FOUT + c4 * 4];
            wt[(c4 * 4 + 0) * 68 + k] = v.x;
            wt[(c4 * 4 + 1) * 68 + k] = v.y;
            wt[(c4 * 4 + 2) * 68 + k] = v.z;
            wt[(c4 * 4 + 3) * 68 + k] = v.w;
        }
        const int rowbase0 = (b - 16) * 256;
        const int rg = t >> 5, cg = t & 31;
        float sums[4] = {0, 0, 0, 0};
        float sqs[4]  = {0, 0, 0, 0};
        for (int sub = 0; sub < 4; sub++) {
            const int rowbase = rowbase0 + sub * 64;
            __syncthreads();
#pragma unroll
            for (int it = 0; it < 2; it++) {
                int lid = t + 512 * it;
                int r = lid >> 4, f4 = lid & 15;
                float4 v = *(const float4*)&feat[(size_t)(rowbase + r) * FIN + f4 * 4];
                *(float4*)&fl[r * 68 + f4 * 4] = v;
            }
            __syncthreads();
            float acc[4][4];
#pragma unroll
            for (int i = 0; i < 4; i++)
#pragma unroll
                for (int j = 0; j < 4; j++) acc[i][j] = 0.f;
#pragma unroll 2
            for (int k4 = 0; k4 < 16; k4++) {
                float4 f4v[4], w4v[4];
#pragma unroll
                for (int i = 0; i < 4; i++) f4v[i] = *(float4*)&fl[(rg * 4 + i) * 68 + k4 * 4];
#pragma unroll
                for (int j = 0; j < 4; j++) w4v[j] = *(float4*)&wt[(cg + 32 * j) * 68 + k4 * 4];
#pragma unroll
                for (int i = 0; i < 4; i++)
#pragma unroll
                    for (int j = 0; j < 4; j++) {
                        acc[i][j] = fmaf(f4v[i].x, w4v[j].x, acc[i][j]);
                        acc[i][j] = fmaf(f4v[i].y, w4v[j].y, acc[i][j]);
                        acc[i][j] = fmaf(f4v[i].z, w4v[j].z, acc[i][j]);
                        acc[i][j] = fmaf(f4v[i].w, w4v[j].w, acc[i][j]);
                    }
            }
#pragma unroll
            for (int j = 0; j < 4; j++) {
                int c = cg + 32 * j;
                float bc = bias[c];
#pragma unroll
                for (int i = 0; i < 4; i++) {
                    float h = acc[i][j] + bc;
                    sums[j] += h; sqs[j] += h * h;
                    hout[(size_t)(rowbase + rg * 4 + i) * FOUT + c] = __float2bfloat16(h);
                }
            }
        }
        __syncthreads();
        float* suml = fl;
        float* sql  = wt;
#pragma unroll
        for (int j = 0; j < 4; j++) {
            suml[rg * FOUT + cg + 32 * j] = sums[j];
            sql[rg * FOUT + cg + 32 * j]  = sqs[j];
        }
        __syncthreads();
        if (t < FOUT) {
            float S = 0.f, Q = 0.f;
#pragma unroll
            for (int r = 0; r < 16; r++) { S += suml[r * FOUT + t]; Q += sql[r * FOUT + t]; }
            atomicAdd(&gsum[t], S);
            atomicAdd(&gsq[t], Q);
        }
    } else {
        // ---------------- xnorm + bf16 hi/lo split (512 threads, 128 blocks)
        int r = (b - 272) * 512 + t;
        const float4* fr = (const float4*)&feat[(size_t)r * FIN];
        unsigned short hrow[64], lrow[64];
        float s = 0.f;
#pragma unroll
        for (int i = 0; i < 16; i++) {
            float4 v = fr[i];
            s += v.x * v.x + v.y * v.y + v.z * v.z + v.w * v.w;
            float vv[4] = {v.x, v.y, v.z, v.w};
#pragma unroll
            for (int j = 0; j < 4; j++) {
                unsigned short h = bf16_rn(vv[j]);
                float hf = __uint_as_float((unsigned)h << 16);
                hrow[4 * i + j] = h;
                lrow[4 * i + j] = bf16_rn(vv[j] - hf);
            }
        }
        xnorm[r] = s;
#pragma unroll
        for (int i = 0; i < 8; i++) {
            short8 hv, lv;
#pragma unroll
            for (int j = 0; j < 8; j++) { hv[j] = (short)hrow[8 * i + j]; lv[j] = (short)lrow[8 * i + j]; }
            *(short8*)&Xhi[(size_t)r * 64 + 8 * i] = hv;
            *(short8*)&Xlo[(size_t)r * 64 + 8 * i] = lv;
        }
    }
}

// ---------------------------------------------------------------- BN finalize
__global__ void finalize_kernel(const float* __restrict__ gsum, const float* __restrict__ gsq,
        const float* __restrict__ gamma, const float* __restrict__ beta,
        float* __restrict__ acoef, float* __restrict__ ccoef) {
    int c = threadIdx.x;
    float mean = gsum[c] * (1.0f / NN);
    float var  = gsq[c] * (1.0f / NN) - mean * mean;
    float s = rsqrtf(var + 1e-5f) * gamma[c];
    acoef[c] = s;
    ccoef[c] = beta[c] - mean * s;
}

// ---------------------------------------------------------------- KNN filter: MFMA + two-phase threshold
// grid 512: cloud(16) x qgroup(16) x half(2). Wave w owns queries qg*64+w*16..+15 vs 2048 points.
// Both streaming loops are software-pipelined: tile t+1's B-fragments + xnorm are
// prefetched into registers before tile t's MFMA chain issues (hides L2/L3 latency
// at the 2-wave/SIMD occupancy this kernel runs at). Math is bit-identical.
__global__ __launch_bounds__(256, 2) void knn_kernel(
        const unsigned short* __restrict__ Xhi, const unsigned short* __restrict__ Xlo,
        const int* __restrict__ fps_idx, const float* __restrict__ xnorm,
        unsigned short* __restrict__ cand) {
    __shared__ float TL[4][16][32];            // [wave][q][col*2+{0,1}] collected values
    __shared__ float TQ[4][16];                // per-query threshold
    __shared__ int   cntL[4][16];
    __shared__ unsigned short buf[4][16][64];
    const int t = threadIdx.x, b = blockIdx.x;
    const int cloud = b & 15, qg = (b >> 4) & 15, half = b >> 8;
    const int wave = t >> 6, lane = t & 63;
    const int quad = lane >> 4, col = lane & 15;
    const int cbase = cloud * NP;
    const int qloc = qg * 64 + wave * 16;

    // A fragments (loop-invariant): A[m=lane&15][k=quad*8+j]
    const int qrow = fps_idx[cloud * MS + qloc + col];
    const unsigned short* Qh = Xhi + (size_t)(cbase + qrow) * 64;
    const unsigned short* Ql = Xlo + (size_t)(cbase + qrow) * 64;
    short8 Ah0 = *(const short8*)(Qh + quad * 8);
    short8 Ah1 = *(const short8*)(Qh + 32 + quad * 8);
    short8 Al0 = *(const short8*)(Ql + quad * 8);
    short8 Al1 = *(const short8*)(Ql + 32 + quad * 8);

    const int pstart = half * 2048;
    // -------- phase 1: unconditional 2-smallest per (lane, r) stream (pipelined)
    float mA[4] = {INFINITY, INFINITY, INFINITY, INFINITY};
    float mB[4] = {INFINITY, INFINITY, INFINITY, INFINITY};
    {
        int pr0 = cbase + pstart + col;
        const unsigned short* Bh0 = Xhi + (size_t)pr0 * 64;
        const unsigned short* Bl0 = Xlo + (size_t)pr0 * 64;
        short8 nh0 = *(const short8*)(Bh0 + quad * 8);
        short8 nh1 = *(const short8*)(Bh0 + 32 + quad * 8);
        short8 nl0 = *(const short8*)(Bl0 + quad * 8);
        short8 nl1 = *(const short8*)(Bl0 + 32 + quad * 8);
        float nxn = xnorm[pr0];
        for (int tile = 0; tile < 128; tile++) {
            short8 bh0 = nh0, bh1 = nh1, bl0 = nl0, bl1 = nl1;
            float xnv = nxn;
            if (tile < 127) {
                const int pr = cbase + pstart + (tile + 1) * 16 + col;
                const unsigned short* Bh = Xhi + (size_t)pr * 64;
                const unsigned short* Bl = Xlo + (size_t)pr * 64;
                nh0 = *(const short8*)(Bh + quad * 8);
                nh1 = *(const short8*)(Bh + 32 + quad * 8);
                nl0 = *(const short8*)(Bl + quad * 8);
                nl1 = *(const short8*)(Bl + 32 + quad * 8);
                nxn = xnorm[pr];
            }
            f32x4 acc = {0.f, 0.f, 0.f, 0.f};
            acc = __builtin_amdgcn_mfma_f32_16x16x32_bf16(Ah0, bh0, acc, 0, 0, 0);
            acc = __builtin_amdgcn_mfma_f32_16x16x32_bf16(Ah1, bh1, acc, 0, 0, 0);
            acc = __builtin_amdgcn_mfma_f32_16x16x32_bf16(Al0, bh0, acc, 0, 0, 0);
            acc = __builtin_amdgcn_mfma_f32_16x16x32_bf16(Al1, bh1, acc, 0, 0, 0);
            acc = __builtin_amdgcn_mfma_f32_16x16x32_bf16(Ah0, bl0, acc, 0, 0, 0);
            acc = __builtin_amdgcn_mfma_f32_16x16x32_bf16(Ah1, bl1, acc, 0, 0, 0);
            // C layout (validated R6/R7): score for query quad*4+r at point pstart+tile*16+col
#pragma unroll
            for (int r = 0; r < 4; r++) {
                float s = fmaf(-2.0f, acc[r], xnv);
                float mx = fmaxf(mA[r], s);
                mA[r] = fminf(mA[r], s);
                mB[r] = fminf(mB[r], mx);
            }
        }
    }
    // -------- threshold: T[q] = 16th smallest of {mA,mB over 16 cols} (wave-local LDS, no barrier)
#pragma unroll
    for (int r = 0; r < 4; r++) {
        TL[wave][quad * 4 + r][col * 2 + 0] = mA[r];
        TL[wave][quad * 4 + r][col * 2 + 1] = mB[r];
    }
    if (lane < 16) cntL[wave][lane] = 0;
    {
        const int q = lane >> 2, j0 = (lane & 3) * 8;
        float v[32];
#pragma unroll
        for (int j = 0; j < 32; j++) v[j] = TL[wave][q][j];
#pragma unroll
        for (int u = 0; u < 8; u++) {
            float vj = TL[wave][q][j0 + u];
            int jj = j0 + u, rank = 0;
#pragma unroll
            for (int k = 0; k < 32; k++)
                rank += (v[k] < vj || (v[k] == vj && k < jj)) ? 1 : 0;
            if (rank == 15) TQ[wave][q] = vj;
        }
    }
    // -------- phase 2: emit candidates below threshold (pipelined)
    float T0 = TQ[wave][quad * 4 + 0] + KNN_MARGIN;
    float T1 = TQ[wave][quad * 4 + 1] + KNN_MARGIN;
    float T2 = TQ[wave][quad * 4 + 2] + KNN_MARGIN;
    float T3 = TQ[wave][quad * 4 + 3] + KNN_MARGIN;
    {
        int pr0 = cbase + pstart + col;
        const unsigned short* Bh0 = Xhi + (size_t)pr0 * 64;
        const unsigned short* Bl0 = Xlo + (size_t)pr0 * 64;
        short8 nh0 = *(const short8*)(Bh0 + quad * 8);
        short8 nh1 = *(const short8*)(Bh0 + 32 + quad * 8);
        short8 nl0 = *(const short8*)(Bl0 + quad * 8);
        short8 nl1 = *(const short8*)(Bl0 + 32 + quad * 8);
        float nxn = xnorm[pr0];
        for (int tile = 0; tile < 128; tile++) {
            short8 bh0 = nh0, bh1 = nh1, bl0 = nl0, bl1 = nl1;
            float xnv = nxn;
            if (tile < 127) {
                const int pr = cbase + pstart + (tile + 1) * 16 + col;
                const unsigned short* Bh = Xhi + (size_t)pr * 64;
                const unsigned short* Bl = Xlo + (size_t)pr * 64;
                nh0 = *(const short8*)(Bh + quad * 8);
                nh1 = *(const short8*)(Bh + 32 + quad * 8);
                nl0 = *(const short8*)(Bl + quad * 8);
                nl1 = *(const short8*)(Bl + 32 + quad * 8);
                nxn = xnorm[pr];
            }
            const int pidx = pstart + tile * 16 + col;
            f32x4 acc = {0.f, 0.f, 0.f, 0.f};
            acc = __builtin_amdgcn_mfma_f32_16x16x32_bf16(Ah0, bh0, acc, 0, 0, 0);
            acc = __builtin_amdgcn_mfma_f32_16x16x32_bf16(Ah1, bh1, acc, 0, 0, 0);
            acc = __builtin_amdgcn_mfma_f32_16x16x32_bf16(Al0, bh0, acc, 0, 0, 0);
            acc = __builtin_amdgcn_mfma_f32_16x16x32_bf16(Al1, bh1, acc, 0, 0, 0);
            acc = __builtin_amdgcn_mfma_f32_16x16x32_bf16(Ah0, bl0, acc, 0, 0, 0);
            acc = __builtin_amdgcn_mfma_f32_16x16x32_bf16(Ah1, bl1, acc, 0, 0, 0);
            float s0 = fmaf(-2.0f, acc[0], xnv);
            float s1 = fmaf(-2.0f, acc[1], xnv);
            float s2 = fmaf(-2.0f, acc[2], xnv);
            float s3 = fmaf(-2.0f, acc[3], xnv);
            if (s0 <= T0) { int p = atomicAdd(&cntL[wave][quad * 4 + 0], 1); if (p < 64) buf[wave][quad * 4 + 0][p] = (unsigned short)pidx; }
            if (s1 <= T1) { int p = atomicAdd(&cntL[wave][quad * 4 + 1], 1); if (p < 64) buf[wave][quad * 4 + 1][p] = (unsigned short)pidx; }
            if (s2 <= T2) { int p = atomicAdd(&cntL[wave][quad * 4 + 2], 1); if (p < 64) buf[wave][quad * 4 + 2][p] = (unsigned short)pidx; }
            if (s3 <= T3) { int p = atomicAdd(&cntL[wave][quad * 4 + 3], 1); if (p < 64) buf[wave][quad * 4 + 3][p] = (unsigned short)pidx; }
        }
    }
    // -------- dump (coalesced 128B per query; sentinel-pad)
#pragma unroll
    for (int q = 0; q < 16; q++) {
        int n = cntL[wave][q];
        unsigned short val = (lane < n) ? buf[wave][q][lane] : (unsigned short)0xFFFF;
        cand[(size_t)(cloud * MS + qloc + q) * 128 + half * 64 + lane] = val;
    }
}

// ---------------------------------------------------------------- refine: exact fp32 top-16 + gather/BN/ReLU/maxpool
// block = one query; 128 candidate slots (sentinel-padded), 2 lanes/candidate.
__global__ __launch_bounds__(256) void refine_kernel(
        const float* __restrict__ feat, const int* __restrict__ fps_idx,
        const float* __restrict__ xnorm, const unsigned short* __restrict__ cand,
        const __hip_bfloat16* __restrict__ h, const float* __restrict__ acoef,
        const float* __restrict__ ccoef, float* __restrict__ out_feat) {
    __shared__ float qlds[64];
    __shared__ float cD[128];
    __shared__ int   cI[128];
    __shared__ int   fIdx[16];
    __shared__ float cf[256];
    const int t = threadIdx.x, b = blockIdx.x;
    const int cloud = b & 15, m = b >> 4;          // cloud <-> XCD locality
    const int q = cloud * MS + m;
    const int cbase = cloud * NP;
    if (t < 128) cf[t] = acoef[t]; else cf[t] = ccoef[t - 128];
    if (t < 16) {
        int qr = fps_idx[q];
        float4 v = ((const float4*)(feat + (size_t)(cbase + qr) * FIN))[t];
        *(float4*)&qlds[t * 4] = v;
    }
    __syncthreads();
    // exact fp32 distance: candidate c = t>>1, half jh = t&1 covers 32 dims
    const int c = t >> 1, jh = t & 1;
    const unsigned short cs = cand[(size_t)q * 128 + c];
    const bool valid = (cs != 0xFFFF);
    const int cidx = valid ? (int)cs : 0;
    const float4* xr = (const float4*)(feat + (size_t)(cbase + cidx) * FIN) + jh * 8;
    float a0 = 0.f, a1 = 0.f, a2 = 0.f, a3 = 0.f;
#pragma unroll
    for (int i = 0; i < 8; i++) {
        float4 x4 = xr[i];
        a0 = fmaf(qlds[jh * 32 + 4 * i + 0], x4.x, a0);
        a1 = fmaf(qlds[jh * 32 + 4 * i + 1], x4.y, a1);
        a2 = fmaf(qlds[jh * 32 + 4 * i + 2], x4.z, a2);
        a3 = fmaf(qlds[jh * 32 + 4 * i + 3], x4.w, a3);
    }
    float a = (a0 + a1) + (a2 + a3);
    a += __shfl_xor(a, 1);
    if (jh == 0) {
        cD[c] = valid ? fmaf(-2.0f, a, xnorm[cbase + cidx]) : INFINITY;
        cI[c] = valid ? cidx : (65536 + c);   // distinct tiebreak ids for sentinels
    }
    __syncthreads();
    // rank-count among 128 (lex (d, idx); >=32 real distinct candidates guaranteed)
    if (t < 128) {
        float dv = cD[t]; int iv = cI[t]; int rank = 0;
#pragma unroll 8
        for (int j = 0; j < 128; j++) {
            float dj = cD[j]; int ij = cI[j];
            rank += (dj < dv || (dj == dv && ij < iv)) ? 1 : 0;
        }
        if (rank < 16) fIdx[rank] = iv;
    }
    __syncthreads();
    // gather + BN affine + relu + maxpool
    if (t < 128) {
        const __hip_bfloat16* hb = h + (size_t)cbase * FOUT;
        const float ac = cf[t], cc = cf[128 + t];
        float mx = -INFINITY;
#pragma unroll
        for (int k = 0; k < 16; k++) {
            int row = fIdx[k];
            float hv = __bfloat162float(hb[(size_t)row * FOUT + t]);
            mx = fmaxf(mx, fmaxf(fmaf(ac, hv, cc), 0.f));
        }
        out_feat[(size_t)q * FOUT + t] = mx;
    }
}

// ---------------------------------------------------------------- launch
extern "C" void kernel_launch(void* const* d_in, const int* in_sizes, int n_in,
                              void* d_out, int out_size, void* d_ws, size_t ws_size,
                              hipStream_t stream) {
    (void)in_sizes; (void)n_in; (void)out_size; (void)ws_size;
    const float* position = (const float*)d_in[0];
    const float* features = (const float*)d_in[1];
    const float* W        = (const float*)d_in[3];
    const float* bias     = (const float*)d_in[4];
    const float* gamma    = (const float*)d_in[5];
    const float* beta     = (const float*)d_in[6];
    float* out = (float*)d_out;

    char* ws = (char*)d_ws;
    int*   fps_idx = (int*)ws;                               // 64 KB
    float* gsum    = (float*)(ws + 65536);                   // 512 B
    float* gsq     = (float*)(ws + 66048);                   // 512 B
    float* acoef   = (float*)(ws + 66560);                   // 512 B
    float* ccoef   = (float*)(ws + 67072);                   // 512 B
    float* xnorm   = (float*)(ws + 67584);                   // 256 KB -> ends 329728
    unsigned short* cand = (unsigned short*)(ws + 329728);   // 4 MB   -> ends 4524032
    unsigned short* Xhi  = (unsigned short*)(ws + 4524032);  // 8 MB   -> ends 12912640
    __hip_bfloat16* hbuf = (__hip_bfloat16*)(ws + 12912640); // 16 MB  -> ends ~29.7 MB

    float* out_feat  = out;                 // [16384][128]
    float* out_pos   = out + 2097152;       // [16384][3]
    float* out_batch = out + 2146304;       // [16384]
    // Stash Xlo in the out_feat region (8 MB exact fit); refine overwrites it afterwards.
    unsigned short* Xlo = (unsigned short*)out;

    hipMemsetAsync(gsum, 0, 1024, stream);  // zero gsum+gsq
    front_kernel<<<400, 512, 0, stream>>>(position, features, W, bias,
                                          fps_idx, out_pos, out_batch, xnorm, Xhi, Xlo,
                                          hbuf, gsum, gsq);
    finalize_kernel<<<1, FOUT, 0, stream>>>(gsum, gsq, gamma, beta, acoef, ccoef);
    knn_kernel<<<512, 256, 0, stream>>>(Xhi, Xlo, fps_idx, xnorm, cand);
    refine_kernel<<<16384, 256, 0, stream>>>(features, fps_idx, xnorm, cand,
                                             hbuf, acoef, ccoef, out_feat);
}

// Round 7
// 957.889 us; speedup vs baseline: 1.1283x; 1.0319x over previous
//
#include <hip/hip_runtime.h>
#include <hip/hip_bf16.h>

#define NB 16
#define NP 4096
#define MS 1024
#define NN 65536
#define FIN 64
#define FOUT 128
#define KNN_MARGIN 0.25f

typedef __attribute__((ext_vector_type(8))) short short8;
typedef __attribute__((ext_vector_type(4))) float f32x4;
typedef __attribute__((ext_vector_type(2))) float f32x2;

// DPP cumulative-max step on a (dist,idx) key, using v_max_f64.
// Keys are positive f64 bit patterns (finite f32 dist in high word => never NaN),
// so IEEE fmax == unsigned 64-bit max. Invalid DPP lanes -> 0.0 (identity).
template <int CTRL>
__device__ __forceinline__ unsigned long long dpp_fmax_step(unsigned long long k) {
    unsigned lo = (unsigned)k, hi = (unsigned)(k >> 32);
    unsigned plo = (unsigned)__builtin_amdgcn_update_dpp(0, (int)lo, CTRL, 0xf, 0xf, true);
    unsigned phi = (unsigned)__builtin_amdgcn_update_dpp(0, (int)hi, CTRL, 0xf, 0xf, true);
    unsigned long long pk = ((unsigned long long)phi << 32) | plo;
    double a = __builtin_bit_cast(double, k);
    double p = __builtin_bit_cast(double, pk);
    return __builtin_bit_cast(unsigned long long, fmax(a, p));
}

__device__ __forceinline__ unsigned short bf16_rn(float v) {
    unsigned u = __float_as_uint(v);
    unsigned r = u + 0x7FFF + ((u >> 16) & 1);
    return (unsigned short)(r >> 16);
}

// ---------------------------------------------------------------- front: FPS + GEMM + xnorm/split fused
__global__ __launch_bounds__(512, 1) void front_kernel(
        const float* __restrict__ pos, const float* __restrict__ feat,
        const float* __restrict__ W, const float* __restrict__ bias,
        int* __restrict__ fps_idx, float* __restrict__ out_pos, float* __restrict__ out_batch,
        float* __restrict__ xnorm, unsigned short* __restrict__ Xhi, unsigned short* __restrict__ Xlo,
        __hip_bfloat16* __restrict__ hout, float* __restrict__ gsum, float* __restrict__ gsq) {
    // FPS view: plds4[4096] float4 (65536 B) + idxL[1024] int (4096 B) + wk[2][8] double (128 B)
    // GEMM view: first 52224 B as floats (wt/fl)
    __shared__ __align__(16) char smraw[69760];
    const int t = threadIdx.x;
    const int b = blockIdx.x;
    if (b < 16) {
        // ---------------- FPS: 512 threads x 8 pts/thread (4 x f32x2 packed pairs)
        // Dist update uses packed FP32 (v_pk_fma/pk_min); combine = R2-proven flat
        // broadcast tree with keys read as double2 (b128 pairs).
        float4* plds4 = (float4*)smraw;
        float*  plin  = (float*)smraw;                    // linear staging view
        int* idxL = (int*)(smraw + 65536);
        double* wk = (double*)(smraw + 65536 + 4096);     // [2][8] per-wave keys (16B aligned)
        const float* pb = pos + (size_t)b * NP * 3;
#pragma unroll
        for (int i = 0; i < 24; i++) { int id = t + 512 * i; plin[id] = pb[id]; }
        __syncthreads();
        f32x2 px2[4], py2[4], pz2[4], dist2[4];
#pragma unroll
        for (int j = 0; j < 4; j++) {
            int p0 = t + 512 * (2 * j), p1 = p0 + 512;
            px2[j] = {plin[p0 * 3 + 0], plin[p1 * 3 + 0]};
            py2[j] = {plin[p0 * 3 + 1], plin[p1 * 3 + 1]};
            pz2[j] = {plin[p0 * 3 + 2], plin[p1 * 3 + 2]};
            dist2[j] = {INFINITY, INFINITY};
        }
        __syncthreads();   // all linear reads done before float4 overwrite
#pragma unroll
        for (int j = 0; j < 4; j++) {
            plds4[t + 512 * (2 * j)]     = (float4){px2[j][0], py2[j][0], pz2[j][0], 0.f};
            plds4[t + 512 * (2 * j + 1)] = (float4){px2[j][1], py2[j][1], pz2[j][1], 0.f};
        }
        if (t == 0) idxL[0] = 0;
        __syncthreads();
        float4 c0 = plds4[0];
        float lx = c0.x, ly = c0.y, lz = c0.z;
        const int ln = t & 63, wv = t >> 6;   // 8 waves
        for (int m = 1; m < MS; m++) {
#pragma unroll
            for (int j = 0; j < 4; j++) {
                f32x2 dx = px2[j] - lx, dy = py2[j] - ly, dz = pz2[j] - lz;
                f32x2 d = dx * dx + dy * dy + dz * dz;
                dist2[j] = __builtin_elementwise_min(dist2[j], d);
            }
            // local argmax tree over the 8 packed dists (i ordering = point t+512*i)
            float d1[4]; int i1[4];
#pragma unroll
            for (int j = 0; j < 4; j++) {
                bool g = dist2[j][1] > dist2[j][0];
                d1[j] = g ? dist2[j][1] : dist2[j][0];
                i1[j] = 2 * j + (g ? 1 : 0);
            }
            float d2[2]; int i2[2];
#pragma unroll
            for (int j = 0; j < 2; j++) {
                bool g = d1[j + 2] > d1[j];
                d2[j] = g ? d1[j + 2] : d1[j]; i2[j] = g ? i1[j + 2] : i1[j];
            }
            bool g3 = d2[1] > d2[0];
            float bd = g3 ? d2[1] : d2[0];
            int bi = g3 ? i2[1] : i2[0];
            int bp = t + (bi << 9);
            unsigned long long key =
                ((unsigned long long)__float_as_uint(bd) << 32) | (unsigned)(~bp);
            key = dpp_fmax_step<0x111>(key);   // row_shr:1
            key = dpp_fmax_step<0x112>(key);   // row_shr:2
            key = dpp_fmax_step<0x114>(key);   // row_shr:4
            key = dpp_fmax_step<0x118>(key);   // row_shr:8
            key = dpp_fmax_step<0x142>(key);   // row_bcast15
            key = dpp_fmax_step<0x143>(key);   // row_bcast31
            const int par = (m & 1) * 8;
            if (ln == 63) wk[par + wv] = __builtin_bit_cast(double, key);
            __syncthreads();
            const double2* wk2 = (const double2*)(wk + par);   // 4 x b128 broadcast reads
            double2 q01 = wk2[0], q23 = wk2[1], q45 = wk2[2], q67 = wk2[3];
            double ka = fmax(q01.x, q01.y), kb = fmax(q23.x, q23.y);
            double kc = fmax(q45.x, q45.y), kd = fmax(q67.x, q67.y);
            ka = fmax(ka, kb);
            kc = fmax(kc, kd);
            unsigned long long kw = __builtin_bit_cast(unsigned long long, fmax(ka, kc));
            bp = (int)(~(unsigned)kw) & 0xFFF;
            float4 c = plds4[bp];                          // one b128 coords read
            lx = c.x; ly = c.y; lz = c.z;
            if (t == 0) idxL[m] = bp;
        }
        __syncthreads();
        for (int m = t; m < MS; m += 512) {
            int ix = idxL[m];
            size_t o = (size_t)b * MS + m;
            fps_idx[o] = ix;
            float4 c = plds4[ix];
            out_pos[o * 3 + 0] = c.x;
            out_pos[o * 3 + 1] = c.y;
            out_pos[o * 3 + 2] = c.z;
            out_batch[o] = (float)b;
        }
    } else if (b < 272) {
        // ---------------- GEMM + BN stats (rows (b-16)*256 .. +255), 512 threads
        float* wt = (float*)smraw;            // [128][68] W^T
        float* fl = (float*)smraw + 8704;     // [64][68] feature tile
#pragma unroll
        for (int it = 0; it < 4; it++) {
            int lid = t + 512 * it;
            int k = lid >> 5, c4 = lid & 31;
            float4 v = *(const float4*)&W[k * FOUT + c4 * 4];
            wt[(c4 * 4 + 0) * 68 + k] = v.x;
            wt[(c4 * 4 + 1) * 68 + k] = v.y;
            wt[(c4 * 4 + 2) * 68 + k] = v.z;
            wt[(c4 * 4 + 3) * 68 + k] = v.w;
        }
        const int rowbase0 = (b - 16) * 256;
        const int rg = t >> 5, cg = t & 31;
        float sums[4] = {0, 0, 0, 0};
        float sqs[4]  = {0, 0, 0, 0};
        for (int sub = 0; sub < 4; sub++) {
            const int rowbase = rowbase0 + sub * 64;
            __syncthreads();
#pragma unroll
            for (int it = 0; it < 2; it++) {
                int lid = t + 512 * it;
                int r = lid >> 4, f4 = lid & 15;
                float4 v = *(const float4*)&feat[(size_t)(rowbase + r) * FIN + f4 * 4];
                *(float4*)&fl[r * 68 + f4 * 4] = v;
            }
            __syncthreads();
            float acc[4][4];
#pragma unroll
            for (int i = 0; i < 4; i++)
#pragma unroll
                for (int j = 0; j < 4; j++) acc[i][j] = 0.f;
#pragma unroll 2
            for (int k4 = 0; k4 < 16; k4++) {
                float4 f4v[4], w4v[4];
#pragma unroll
                for (int i = 0; i < 4; i++) f4v[i] = *(float4*)&fl[(rg * 4 + i) * 68 + k4 * 4];
#pragma unroll
                for (int j = 0; j < 4; j++) w4v[j] = *(float4*)&wt[(cg + 32 * j) * 68 + k4 * 4];
#pragma unroll
                for (int i = 0; i < 4; i++)
#pragma unroll
                    for (int j = 0; j < 4; j++) {
                        acc[i][j] = fmaf(f4v[i].x, w4v[j].x, acc[i][j]);
                        acc[i][j] = fmaf(f4v[i].y, w4v[j].y, acc[i][j]);
                        acc[i][j] = fmaf(f4v[i].z, w4v[j].z, acc[i][j]);
                        acc[i][j] = fmaf(f4v[i].w, w4v[j].w, acc[i][j]);
                    }
            }
#pragma unroll
            for (int j = 0; j < 4; j++) {
                int c = cg + 32 * j;
                float bc = bias[c];
#pragma unroll
                for (int i = 0; i < 4; i++) {
                    float h = acc[i][j] + bc;
                    sums[j] += h; sqs[j] += h * h;
                    hout[(size_t)(rowbase + rg * 4 + i) * FOUT + c] = __float2bfloat16(h);
                }
            }
        }
        __syncthreads();
        float* suml = fl;
        float* sql  = wt;
#pragma unroll
        for (int j = 0; j < 4; j++) {
            suml[rg * FOUT + cg + 32 * j] = sums[j];
            sql[rg * FOUT + cg + 32 * j]  = sqs[j];
        }
        __syncthreads();
        if (t < FOUT) {
            float S = 0.f, Q = 0.f;
#pragma unroll
            for (int r = 0; r < 16; r++) { S += suml[r * FOUT + t]; Q += sql[r * FOUT + t]; }
            atomicAdd(&gsum[t], S);
            atomicAdd(&gsq[t], Q);
        }
    } else {
        // ---------------- xnorm + bf16 hi/lo split (512 threads, 128 blocks)
        int r = (b - 272) * 512 + t;
        const float4* fr = (const float4*)&feat[(size_t)r * FIN];
        unsigned short hrow[64], lrow[64];
        float s = 0.f;
#pragma unroll
        for (int i = 0; i < 16; i++) {
            float4 v = fr[i];
            s += v.x * v.x + v.y * v.y + v.z * v.z + v.w * v.w;
            float vv[4] = {v.x, v.y, v.z, v.w};
#pragma unroll
            for (int j = 0; j < 4; j++) {
                unsigned short h = bf16_rn(vv[j]);
                float hf = __uint_as_float((unsigned)h << 16);
                hrow[4 * i + j] = h;
                lrow[4 * i + j] = bf16_rn(vv[j] - hf);
            }
        }
        xnorm[r] = s;
#pragma unroll
        for (int i = 0; i < 8; i++) {
            short8 hv, lv;
#pragma unroll
            for (int j = 0; j < 8; j++) { hv[j] = (short)hrow[8 * i + j]; lv[j] = (short)lrow[8 * i + j]; }
            *(short8*)&Xhi[(size_t)r * 64 + 8 * i] = hv;
            *(short8*)&Xlo[(size_t)r * 64 + 8 * i] = lv;
        }
    }
}

// ---------------------------------------------------------------- BN finalize
__global__ void finalize_kernel(const float* __restrict__ gsum, const float* __restrict__ gsq,
        const float* __restrict__ gamma, const float* __restrict__ beta,
        float* __restrict__ acoef, float* __restrict__ ccoef) {
    int c = threadIdx.x;
    float mean = gsum[c] * (1.0f / NN);
    float var  = gsq[c] * (1.0f / NN) - mean * mean;
    float s = rsqrtf(var + 1e-5f) * gamma[c];
    acoef[c] = s;
    ccoef[c] = beta[c] - mean * s;
}

// ---------------------------------------------------------------- KNN filter: MFMA + two-phase threshold
// grid 512: cloud(16) x qgroup(16) x half(2). Wave w owns queries qg*64+w*16..+15 vs 2048 points.
// Both streaming loops are software-pipelined: tile t+1's B-fragments + xnorm are
// prefetched into registers before tile t's MFMA chain issues. Math is bit-identical.
__global__ __launch_bounds__(256, 2) void knn_kernel(
        const unsigned short* __restrict__ Xhi, const unsigned short* __restrict__ Xlo,
        const int* __restrict__ fps_idx, const float* __restrict__ xnorm,
        unsigned short* __restrict__ cand) {
    __shared__ float TL[4][16][32];            // [wave][q][col*2+{0,1}] collected values
    __shared__ float TQ[4][16];                // per-query threshold
    __shared__ int   cntL[4][16];
    __shared__ unsigned short buf[4][16][64];
    const int t = threadIdx.x, b = blockIdx.x;
    const int cloud = b & 15, qg = (b >> 4) & 15, half = b >> 8;
    const int wave = t >> 6, lane = t & 63;
    const int quad = lane >> 4, col = lane & 15;
    const int cbase = cloud * NP;
    const int qloc = qg * 64 + wave * 16;

    // A fragments (loop-invariant): A[m=lane&15][k=quad*8+j]
    const int qrow = fps_idx[cloud * MS + qloc + col];
    const unsigned short* Qh = Xhi + (size_t)(cbase + qrow) * 64;
    const unsigned short* Ql = Xlo + (size_t)(cbase + qrow) * 64;
    short8 Ah0 = *(const short8*)(Qh + quad * 8);
    short8 Ah1 = *(const short8*)(Qh + 32 + quad * 8);
    short8 Al0 = *(const short8*)(Ql + quad * 8);
    short8 Al1 = *(const short8*)(Ql + 32 + quad * 8);

    const int pstart = half * 2048;
    // -------- phase 1: unconditional 2-smallest per (lane, r) stream (pipelined)
    float mA[4] = {INFINITY, INFINITY, INFINITY, INFINITY};
    float mB[4] = {INFINITY, INFINITY, INFINITY, INFINITY};
    {
        int pr0 = cbase + pstart + col;
        const unsigned short* Bh0 = Xhi + (size_t)pr0 * 64;
        const unsigned short* Bl0 = Xlo + (size_t)pr0 * 64;
        short8 nh0 = *(const short8*)(Bh0 + quad * 8);
        short8 nh1 = *(const short8*)(Bh0 + 32 + quad * 8);
        short8 nl0 = *(const short8*)(Bl0 + quad * 8);
        short8 nl1 = *(const short8*)(Bl0 + 32 + quad * 8);
        float nxn = xnorm[pr0];
        for (int tile = 0; tile < 128; tile++) {
            short8 bh0 = nh0, bh1 = nh1, bl0 = nl0, bl1 = nl1;
            float xnv = nxn;
            if (tile < 127) {
                const int pr = cbase + pstart + (tile + 1) * 16 + col;
                const unsigned short* Bh = Xhi + (size_t)pr * 64;
                const unsigned short* Bl = Xlo + (size_t)pr * 64;
                nh0 = *(const short8*)(Bh + quad * 8);
                nh1 = *(const short8*)(Bh + 32 + quad * 8);
                nl0 = *(const short8*)(Bl + quad * 8);
                nl1 = *(const short8*)(Bl + 32 + quad * 8);
                nxn = xnorm[pr];
            }
            f32x4 acc = {0.f, 0.f, 0.f, 0.f};
            acc = __builtin_amdgcn_mfma_f32_16x16x32_bf16(Ah0, bh0, acc, 0, 0, 0);
            acc = __builtin_amdgcn_mfma_f32_16x16x32_bf16(Ah1, bh1, acc, 0, 0, 0);
            acc = __builtin_amdgcn_mfma_f32_16x16x32_bf16(Al0, bh0, acc, 0, 0, 0);
            acc = __builtin_amdgcn_mfma_f32_16x16x32_bf16(Al1, bh1, acc, 0, 0, 0);
            acc = __builtin_amdgcn_mfma_f32_16x16x32_bf16(Ah0, bl0, acc, 0, 0, 0);
            acc = __builtin_amdgcn_mfma_f32_16x16x32_bf16(Ah1, bl1, acc, 0, 0, 0);
            // C layout (validated R6/R7): score for query quad*4+r at point pstart+tile*16+col
#pragma unroll
            for (int r = 0; r < 4; r++) {
                float s = fmaf(-2.0f, acc[r], xnv);
                float mx = fmaxf(mA[r], s);
                mA[r] = fminf(mA[r], s);
                mB[r] = fminf(mB[r], mx);
            }
        }
    }
    // -------- threshold: T[q] = 16th smallest of {mA,mB over 16 cols} (wave-local LDS, no barrier)
#pragma unroll
    for (int r = 0; r < 4; r++) {
        TL[wave][quad * 4 + r][col * 2 + 0] = mA[r];
        TL[wave][quad * 4 + r][col * 2 + 1] = mB[r];
    }
    if (lane < 16) cntL[wave][lane] = 0;
    {
        const int q = lane >> 2, j0 = (lane & 3) * 8;
        float v[32];
#pragma unroll
        for (int j = 0; j < 32; j++) v[j] = TL[wave][q][j];
#pragma unroll
        for (int u = 0; u < 8; u++) {
            float vj = TL[wave][q][j0 + u];
            int jj = j0 + u, rank = 0;
#pragma unroll
            for (int k = 0; k < 32; k++)
                rank += (v[k] < vj || (v[k] == vj && k < jj)) ? 1 : 0;
            if (rank == 15) TQ[wave][q] = vj;
        }
    }
    // -------- phase 2: emit candidates below threshold (pipelined)
    float T0 = TQ[wave][quad * 4 + 0] + KNN_MARGIN;
    float T1 = TQ[wave][quad * 4 + 1] + KNN_MARGIN;
    float T2 = TQ[wave][quad * 4 + 2] + KNN_MARGIN;
    float T3 = TQ[wave][quad * 4 + 3] + KNN_MARGIN;
    {
        int pr0 = cbase + pstart + col;
        const unsigned short* Bh0 = Xhi + (size_t)pr0 * 64;
        const unsigned short* Bl0 = Xlo + (size_t)pr0 * 64;
        short8 nh0 = *(const short8*)(Bh0 + quad * 8);
        short8 nh1 = *(const short8*)(Bh0 + 32 + quad * 8);
        short8 nl0 = *(const short8*)(Bl0 + quad * 8);
        short8 nl1 = *(const short8*)(Bl0 + 32 + quad * 8);
        float nxn = xnorm[pr0];
        for (int tile = 0; tile < 128; tile++) {
            short8 bh0 = nh0, bh1 = nh1, bl0 = nl0, bl1 = nl1;
            float xnv = nxn;
            if (tile < 127) {
                const int pr = cbase + pstart + (tile + 1) * 16 + col;
                const unsigned short* Bh = Xhi + (size_t)pr * 64;
                const unsigned short* Bl = Xlo + (size_t)pr * 64;
                nh0 = *(const short8*)(Bh + quad * 8);
                nh1 = *(const short8*)(Bh + 32 + quad * 8);
                nl0 = *(const short8*)(Bl + quad * 8);
                nl1 = *(const short8*)(Bl + 32 + quad * 8);
                nxn = xnorm[pr];
            }
            const int pidx = pstart + tile * 16 + col;
            f32x4 acc = {0.f, 0.f, 0.f, 0.f};
            acc = __builtin_amdgcn_mfma_f32_16x16x32_bf16(Ah0, bh0, acc, 0, 0, 0);
            acc = __builtin_amdgcn_mfma_f32_16x16x32_bf16(Ah1, bh1, acc, 0, 0, 0);
            acc = __builtin_amdgcn_mfma_f32_16x16x32_bf16(Al0, bh0, acc, 0, 0, 0);
            acc = __builtin_amdgcn_mfma_f32_16x16x32_bf16(Al1, bh1, acc, 0, 0, 0);
            acc = __builtin_amdgcn_mfma_f32_16x16x32_bf16(Ah0, bl0, acc, 0, 0, 0);
            acc = __builtin_amdgcn_mfma_f32_16x16x32_bf16(Ah1, bl1, acc, 0, 0, 0);
            float s0 = fmaf(-2.0f, acc[0], xnv);
            float s1 = fmaf(-2.0f, acc[1], xnv);
            float s2 = fmaf(-2.0f, acc[2], xnv);
            float s3 = fmaf(-2.0f, acc[3], xnv);
            if (s0 <= T0) { int p = atomicAdd(&cntL[wave][quad * 4 + 0], 1); if (p < 64) buf[wave][quad * 4 + 0][p] = (unsigned short)pidx; }
            if (s1 <= T1) { int p = atomicAdd(&cntL[wave][quad * 4 + 1], 1); if (p < 64) buf[wave][quad * 4 + 1][p] = (unsigned short)pidx; }
            if (s2 <= T2) { int p = atomicAdd(&cntL[wave][quad * 4 + 2], 1); if (p < 64) buf[wave][quad * 4 + 2][p] = (unsigned short)pidx; }
            if (s3 <= T3) { int p = atomicAdd(&cntL[wave][quad * 4 + 3], 1); if (p < 64) buf[wave][quad * 4 + 3][p] = (unsigned short)pidx; }
        }
    }
    // -------- dump (coalesced 128B per query; sentinel-pad)
#pragma unroll
    for (int q = 0; q < 16; q++) {
        int n = cntL[wave][q];
        unsigned short val = (lane < n) ? buf[wave][q][lane] : (unsigned short)0xFFFF;
        cand[(size_t)(cloud * MS + qloc + q) * 128 + half * 64 + lane] = val;
    }
}

// ---------------------------------------------------------------- refine: exact fp32 top-16 + gather/BN/ReLU/maxpool
// block = one query; 128 candidate slots (sentinel-padded), 2 lanes/candidate.
__global__ __launch_bounds__(256) void refine_kernel(
        const float* __restrict__ feat, const int* __restrict__ fps_idx,
        const float* __restrict__ xnorm, const unsigned short* __restrict__ cand,
        const __hip_bfloat16* __restrict__ h, const float* __restrict__ acoef,
        const float* __restrict__ ccoef, float* __restrict__ out_feat) {
    __shared__ float qlds[64];
    __shared__ float cD[128];
    __shared__ int   cI[128];
    __shared__ int   fIdx[16];
    __shared__ float cf[256];
    const int t = threadIdx.x, b = blockIdx.x;
    const int cloud = b & 15, m = b >> 4;          // cloud <-> XCD locality
    const int q = cloud * MS + m;
    const int cbase = cloud * NP;
    if (t < 128) cf[t] = acoef[t]; else cf[t] = ccoef[t - 128];
    if (t < 16) {
        int qr = fps_idx[q];
        float4 v = ((const float4*)(feat + (size_t)(cbase + qr) * FIN))[t];
        *(float4*)&qlds[t * 4] = v;
    }
    __syncthreads();
    // exact fp32 distance: candidate c = t>>1, half jh = t&1 covers 32 dims
    const int c = t >> 1, jh = t & 1;
    const unsigned short cs = cand[(size_t)q * 128 + c];
    const bool valid = (cs != 0xFFFF);
    const int cidx = valid ? (int)cs : 0;
    const float4* xr = (const float4*)(feat + (size_t)(cbase + cidx) * FIN) + jh * 8;
    float a0 = 0.f, a1 = 0.f, a2 = 0.f, a3 = 0.f;
#pragma unroll
    for (int i = 0; i < 8; i++) {
        float4 x4 = xr[i];
        a0 = fmaf(qlds[jh * 32 + 4 * i + 0], x4.x, a0);
        a1 = fmaf(qlds[jh * 32 + 4 * i + 1], x4.y, a1);
        a2 = fmaf(qlds[jh * 32 + 4 * i + 2], x4.z, a2);
        a3 = fmaf(qlds[jh * 32 + 4 * i + 3], x4.w, a3);
    }
    float a = (a0 + a1) + (a2 + a3);
    a += __shfl_xor(a, 1);
    if (jh == 0) {
        cD[c] = valid ? fmaf(-2.0f, a, xnorm[cbase + cidx]) : INFINITY;
        cI[c] = valid ? cidx : (65536 + c);   // distinct tiebreak ids for sentinels
    }
    __syncthreads();
    // rank-count among 128 (lex (d, idx); >=32 real distinct candidates guaranteed)
    if (t < 128) {
        float dv = cD[t]; int iv = cI[t]; int rank = 0;
#pragma unroll 8
        for (int j = 0; j < 128; j++) {
            float dj = cD[j]; int ij = cI[j];
            rank += (dj < dv || (dj == dv && ij < iv)) ? 1 : 0;
        }
        if (rank < 16) fIdx[rank] = iv;
    }
    __syncthreads();
    // gather + BN affine + relu + maxpool
    if (t < 128) {
        const __hip_bfloat16* hb = h + (size_t)cbase * FOUT;
        const float ac = cf[t], cc = cf[128 + t];
        float mx = -INFINITY;
#pragma unroll
        for (int k = 0; k < 16; k++) {
            int row = fIdx[k];
            float hv = __bfloat162float(hb[(size_t)row * FOUT + t]);
            mx = fmaxf(mx, fmaxf(fmaf(ac, hv, cc), 0.f));
        }
        out_feat[(size_t)q * FOUT + t] = mx;
    }
}

// ---------------------------------------------------------------- launch
extern "C" void kernel_launch(void* const* d_in, const int* in_sizes, int n_in,
                              void* d_out, int out_size, void* d_ws, size_t ws_size,
                              hipStream_t stream) {
    (void)in_sizes; (void)n_in; (void)out_size; (void)ws_size;
    const float* position = (const float*)d_in[0];
    const float* features = (const float*)d_in[1];
    const float* W        = (const float*)d_in[3];
    const float* bias     = (const float*)d_in[4];
    const float* gamma    = (const float*)d_in[5];
    const float* beta     = (const float*)d_in[6];
    float* out = (float*)d_out;

    char* ws = (char*)d_ws;
    int*   fps_idx = (int*)ws;                               // 64 KB
    float* gsum    = (float*)(ws + 65536);                   // 512 B
    float* gsq     = (float*)(ws + 66048);                   // 512 B
    float* acoef   = (float*)(ws + 66560);                   // 512 B
    float* ccoef   = (float*)(ws + 67072);                   // 512 B
    float* xnorm   = (float*)(ws + 67584);                   // 256 KB -> ends 329728
    unsigned short* cand = (unsigned short*)(ws + 329728);   // 4 MB   -> ends 4524032
    unsigned short* Xhi  = (unsigned short*)(ws + 4524032);  // 8 MB   -> ends 12912640
    __hip_bfloat16* hbuf = (__hip_bfloat16*)(ws + 12912640); // 16 MB  -> ends ~29.7 MB

    float* out_feat  = out;                 // [16384][128]
    float* out_pos   = out + 2097152;       // [16384][3]
    float* out_batch = out + 2146304;       // [16384]
    // Stash Xlo in the out_feat region (8 MB exact fit); refine overwrites it afterwards.
    unsigned short* Xlo = (unsigned short*)out;

    hipMemsetAsync(gsum, 0, 1024, stream);  // zero gsum+gsq
    front_kernel<<<400, 512, 0, stream>>>(position, features, W, bias,
                                          fps_idx, out_pos, out_batch, xnorm, Xhi, Xlo,
                                          hbuf, gsum, gsq);
    finalize_kernel<<<1, FOUT, 0, stream>>>(gsum, gsq, gamma, beta, acoef, ccoef);
    knn_kernel<<<512, 256, 0, stream>>>(Xhi, Xlo, fps_idx, xnorm, cand);
    refine_kernel<<<16384, 256, 0, stream>>>(features, fps_idx, xnorm, cand,
                                             hbuf, acoef, ccoef, out_feat);
}

// Round 8
// 957.496 us; speedup vs baseline: 1.1288x; 1.0004x over previous
//
#include <hip/hip_runtime.h>
#include <hip/hip_bf16.h>

#define NB 16
#define NP 4096
#define MS 1024
#define NN 65536
#define FIN 64
#define FOUT 128
#define KNN_MARGIN 0.25f

typedef __attribute__((ext_vector_type(8))) short short8;
typedef __attribute__((ext_vector_type(4))) float f32x4;
typedef __attribute__((ext_vector_type(2))) float f32x2;

// DPP cumulative-max step on a (dist,idx) key, using v_max_f64.
// Keys are positive f64 bit patterns (finite f32 dist in high word => never NaN),
// so IEEE fmax == unsigned 64-bit max. Invalid DPP lanes -> 0.0 (identity).
template <int CTRL>
__device__ __forceinline__ unsigned long long dpp_fmax_step(unsigned long long k) {
    unsigned lo = (unsigned)k, hi = (unsigned)(k >> 32);
    unsigned plo = (unsigned)__builtin_amdgcn_update_dpp(0, (int)lo, CTRL, 0xf, 0xf, true);
    unsigned phi = (unsigned)__builtin_amdgcn_update_dpp(0, (int)hi, CTRL, 0xf, 0xf, true);
    unsigned long long pk = ((unsigned long long)phi << 32) | plo;
    double a = __builtin_bit_cast(double, k);
    double p = __builtin_bit_cast(double, pk);
    return __builtin_bit_cast(unsigned long long, fmax(a, p));
}

__device__ __forceinline__ unsigned short bf16_rn(float v) {
    unsigned u = __float_as_uint(v);
    unsigned r = u + 0x7FFF + ((u >> 16) & 1);
    return (unsigned short)(r >> 16);
}

// ---------------------------------------------------------------- front: FPS + GEMM + xnorm/split fused
__global__ __launch_bounds__(512, 1) void front_kernel(
        const float* __restrict__ pos, const float* __restrict__ feat,
        const float* __restrict__ W, const float* __restrict__ bias,
        int* __restrict__ fps_idx, float* __restrict__ out_pos, float* __restrict__ out_batch,
        float* __restrict__ xnorm, unsigned short* __restrict__ Xhi, unsigned short* __restrict__ Xlo,
        __hip_bfloat16* __restrict__ hout, float* __restrict__ gsum, float* __restrict__ gsq) {
    // FPS view: plds4[4096] float4 (65536 B) + idxL[1024] int (4096 B) + wk[2][8] double (128 B)
    // GEMM view: first 52224 B as floats (wt/fl)
    __shared__ __align__(16) char smraw[69760];
    const int t = threadIdx.x;
    const int b = blockIdx.x;
    if (b < 16) {
        // ---------------- FPS: 512 threads x 8 pts/thread (4 x f32x2 packed pairs)
        // Dist update uses packed FP32 (v_pk_fma/pk_min); combine = R2-proven flat
        // broadcast tree with keys read as double2 (b128 pairs).
        float4* plds4 = (float4*)smraw;
        float*  plin  = (float*)smraw;                    // linear staging view
        int* idxL = (int*)(smraw + 65536);
        double* wk = (double*)(smraw + 65536 + 4096);     // [2][8] per-wave keys (16B aligned)
        const float* pb = pos + (size_t)b * NP * 3;
#pragma unroll
        for (int i = 0; i < 24; i++) { int id = t + 512 * i; plin[id] = pb[id]; }
        __syncthreads();
        f32x2 px2[4], py2[4], pz2[4], dist2[4];
#pragma unroll
        for (int j = 0; j < 4; j++) {
            int p0 = t + 512 * (2 * j), p1 = p0 + 512;
            px2[j] = {plin[p0 * 3 + 0], plin[p1 * 3 + 0]};
            py2[j] = {plin[p0 * 3 + 1], plin[p1 * 3 + 1]};
            pz2[j] = {plin[p0 * 3 + 2], plin[p1 * 3 + 2]};
            dist2[j] = {INFINITY, INFINITY};
        }
        __syncthreads();   // all linear reads done before float4 overwrite
#pragma unroll
        for (int j = 0; j < 4; j++) {
            plds4[t + 512 * (2 * j)]     = (float4){px2[j][0], py2[j][0], pz2[j][0], 0.f};
            plds4[t + 512 * (2 * j + 1)] = (float4){px2[j][1], py2[j][1], pz2[j][1], 0.f};
        }
        if (t == 0) idxL[0] = 0;
        __syncthreads();
        float4 c0 = plds4[0];
        float lx = c0.x, ly = c0.y, lz = c0.z;
        const int ln = t & 63, wv = t >> 6;   // 8 waves
        for (int m = 1; m < MS; m++) {
#pragma unroll
            for (int j = 0; j < 4; j++) {
                f32x2 dx = px2[j] - lx, dy = py2[j] - ly, dz = pz2[j] - lz;
                f32x2 d = dx * dx + dy * dy + dz * dz;
                dist2[j] = __builtin_elementwise_min(dist2[j], d);
            }
            // local argmax tree over the 8 packed dists (i ordering = point t+512*i)
            float d1[4]; int i1[4];
#pragma unroll
            for (int j = 0; j < 4; j++) {
                bool g = dist2[j][1] > dist2[j][0];
                d1[j] = g ? dist2[j][1] : dist2[j][0];
                i1[j] = 2 * j + (g ? 1 : 0);
            }
            float d2[2]; int i2[2];
#pragma unroll
            for (int j = 0; j < 2; j++) {
                bool g = d1[j + 2] > d1[j];
                d2[j] = g ? d1[j + 2] : d1[j]; i2[j] = g ? i1[j + 2] : i1[j];
            }
            bool g3 = d2[1] > d2[0];
            float bd = g3 ? d2[1] : d2[0];
            int bi = g3 ? i2[1] : i2[0];
            int bp = t + (bi << 9);
            unsigned long long key =
                ((unsigned long long)__float_as_uint(bd) << 32) | (unsigned)(~bp);
            key = dpp_fmax_step<0x111>(key);   // row_shr:1
            key = dpp_fmax_step<0x112>(key);   // row_shr:2
            key = dpp_fmax_step<0x114>(key);   // row_shr:4
            key = dpp_fmax_step<0x118>(key);   // row_shr:8
            key = dpp_fmax_step<0x142>(key);   // row_bcast15
            key = dpp_fmax_step<0x143>(key);   // row_bcast31
            const int par = (m & 1) * 8;
            if (ln == 63) wk[par + wv] = __builtin_bit_cast(double, key);
            __syncthreads();
            const double2* wk2 = (const double2*)(wk + par);   // 4 x b128 broadcast reads
            double2 q01 = wk2[0], q23 = wk2[1], q45 = wk2[2], q67 = wk2[3];
            double ka = fmax(q01.x, q01.y), kb = fmax(q23.x, q23.y);
            double kc = fmax(q45.x, q45.y), kd = fmax(q67.x, q67.y);
            ka = fmax(ka, kb);
            kc = fmax(kc, kd);
            unsigned long long kw = __builtin_bit_cast(unsigned long long, fmax(ka, kc));
            bp = (int)(~(unsigned)kw) & 0xFFF;
            float4 c = plds4[bp];                          // one b128 coords read
            lx = c.x; ly = c.y; lz = c.z;
            if (t == 0) idxL[m] = bp;
        }
        __syncthreads();
        for (int m = t; m < MS; m += 512) {
            int ix = idxL[m];
            size_t o = (size_t)b * MS + m;
            fps_idx[o] = ix;
            float4 c = plds4[ix];
            out_pos[o * 3 + 0] = c.x;
            out_pos[o * 3 + 1] = c.y;
            out_pos[o * 3 + 2] = c.z;
            out_batch[o] = (float)b;
        }
    } else if (b < 272) {
        // ---------------- GEMM + BN stats (rows (b-16)*256 .. +255), 512 threads
        float* wt = (float*)smraw;            // [128][68] W^T
        float* fl = (float*)smraw + 8704;     // [64][68] feature tile
#pragma unroll
        for (int it = 0; it < 4; it++) {
            int lid = t + 512 * it;
            int k = lid >> 5, c4 = lid & 31;
            float4 v = *(const float4*)&W[k * FOUT + c4 * 4];
            wt[(c4 * 4 + 0) * 68 + k] = v.x;
            wt[(c4 * 4 + 1) * 68 + k] = v.y;
            wt[(c4 * 4 + 2) * 68 + k] = v.z;
            wt[(c4 * 4 + 3) * 68 + k] = v.w;
        }
        const int rowbase0 = (b - 16) * 256;
        const int rg = t >> 5, cg = t & 31;
        float sums[4] = {0, 0, 0, 0};
        float sqs[4]  = {0, 0, 0, 0};
        for (int sub = 0; sub < 4; sub++) {
            const int rowbase = rowbase0 + sub * 64;
            __syncthreads();
#pragma unroll
            for (int it = 0; it < 2; it++) {
                int lid = t + 512 * it;
                int r = lid >> 4, f4 = lid & 15;
                float4 v = *(const float4*)&feat[(size_t)(rowbase + r) * FIN + f4 * 4];
                *(float4*)&fl[r * 68 + f4 * 4] = v;
            }
            __syncthreads();
            float acc[4][4];
#pragma unroll
            for (int i = 0; i < 4; i++)
#pragma unroll
                for (int j = 0; j < 4; j++) acc[i][j] = 0.f;
#pragma unroll 2
            for (int k4 = 0; k4 < 16; k4++) {
                float4 f4v[4], w4v[4];
#pragma unroll
                for (int i = 0; i < 4; i++) f4v[i] = *(float4*)&fl[(rg * 4 + i) * 68 + k4 * 4];
#pragma unroll
                for (int j = 0; j < 4; j++) w4v[j] = *(float4*)&wt[(cg + 32 * j) * 68 + k4 * 4];
#pragma unroll
                for (int i = 0; i < 4; i++)
#pragma unroll
                    for (int j = 0; j < 4; j++) {
                        acc[i][j] = fmaf(f4v[i].x, w4v[j].x, acc[i][j]);
                        acc[i][j] = fmaf(f4v[i].y, w4v[j].y, acc[i][j]);
                        acc[i][j] = fmaf(f4v[i].z, w4v[j].z, acc[i][j]);
                        acc[i][j] = fmaf(f4v[i].w, w4v[j].w, acc[i][j]);
                    }
            }
#pragma unroll
            for (int j = 0; j < 4; j++) {
                int c = cg + 32 * j;
                float bc = bias[c];
#pragma unroll
                for (int i = 0; i < 4; i++) {
                    float h = acc[i][j] + bc;
                    sums[j] += h; sqs[j] += h * h;
                    hout[(size_t)(rowbase + rg * 4 + i) * FOUT + c] = __float2bfloat16(h);
                }
            }
        }
        __syncthreads();
        float* suml = fl;
        float* sql  = wt;
#pragma unroll
        for (int j = 0; j < 4; j++) {
            suml[rg * FOUT + cg + 32 * j] = sums[j];
            sql[rg * FOUT + cg + 32 * j]  = sqs[j];
        }
        __syncthreads();
        if (t < FOUT) {
            float S = 0.f, Q = 0.f;
#pragma unroll
            for (int r = 0; r < 16; r++) { S += suml[r * FOUT + t]; Q += sql[r * FOUT + t]; }
            atomicAdd(&gsum[t], S);
            atomicAdd(&gsq[t], Q);
        }
    } else {
        // ---------------- xnorm + bf16 hi/lo split (512 threads, 128 blocks)
        int r = (b - 272) * 512 + t;
        const float4* fr = (const float4*)&feat[(size_t)r * FIN];
        unsigned short hrow[64], lrow[64];
        float s = 0.f;
#pragma unroll
        for (int i = 0; i < 16; i++) {
            float4 v = fr[i];
            s += v.x * v.x + v.y * v.y + v.z * v.z + v.w * v.w;
            float vv[4] = {v.x, v.y, v.z, v.w};
#pragma unroll
            for (int j = 0; j < 4; j++) {
                unsigned short h = bf16_rn(vv[j]);
                float hf = __uint_as_float((unsigned)h << 16);
                hrow[4 * i + j] = h;
                lrow[4 * i + j] = bf16_rn(vv[j] - hf);
            }
        }
        xnorm[r] = s;
#pragma unroll
        for (int i = 0; i < 8; i++) {
            short8 hv, lv;
#pragma unroll
            for (int j = 0; j < 8; j++) { hv[j] = (short)hrow[8 * i + j]; lv[j] = (short)lrow[8 * i + j]; }
            *(short8*)&Xhi[(size_t)r * 64 + 8 * i] = hv;
            *(short8*)&Xlo[(size_t)r * 64 + 8 * i] = lv;
        }
    }
}

// ---------------------------------------------------------------- BN finalize
__global__ void finalize_kernel(const float* __restrict__ gsum, const float* __restrict__ gsq,
        const float* __restrict__ gamma, const float* __restrict__ beta,
        float* __restrict__ acoef, float* __restrict__ ccoef) {
    int c = threadIdx.x;
    float mean = gsum[c] * (1.0f / NN);
    float var  = gsq[c] * (1.0f / NN) - mean * mean;
    float s = rsqrtf(var + 1e-5f) * gamma[c];
    acoef[c] = s;
    ccoef[c] = beta[c] - mean * s;
}

// ---------------------------------------------------------------- KNN filter: MFMA + two-phase threshold
// grid 512: cloud(16) x qgroup(16) x half(2). Wave w owns queries qg*64+w*16..+15 vs 2048 points.
// Depth-2 software pipeline (manual unroll-by-2, two named register slots): tile t's
// MFMAs run while tiles t+1 and t+2 are in flight -> covers ~2x compute of L2 latency.
// Math / emission bit-identical to the depth-1 version.
#define KNN_LOAD(SLOT_H0, SLOT_H1, SLOT_L0, SLOT_L1, SLOT_XN, TILE)                     \
    {                                                                                   \
        const int pr_ = cbase + pstart + (TILE) * 16 + col;                             \
        const unsigned short* Bh_ = Xhi + (size_t)pr_ * 64;                             \
        const unsigned short* Bl_ = Xlo + (size_t)pr_ * 64;                             \
        SLOT_H0 = *(const short8*)(Bh_ + quad * 8);                                     \
        SLOT_H1 = *(const short8*)(Bh_ + 32 + quad * 8);                                \
        SLOT_L0 = *(const short8*)(Bl_ + quad * 8);                                     \
        SLOT_L1 = *(const short8*)(Bl_ + 32 + quad * 8);                                \
        SLOT_XN = xnorm[pr_];                                                           \
    }

#define KNN_MFMA(ACC, H0, H1, L0, L1)                                                   \
    ACC = __builtin_amdgcn_mfma_f32_16x16x32_bf16(Ah0, H0, ACC, 0, 0, 0);               \
    ACC = __builtin_amdgcn_mfma_f32_16x16x32_bf16(Ah1, H1, ACC, 0, 0, 0);               \
    ACC = __builtin_amdgcn_mfma_f32_16x16x32_bf16(Al0, H0, ACC, 0, 0, 0);               \
    ACC = __builtin_amdgcn_mfma_f32_16x16x32_bf16(Al1, H1, ACC, 0, 0, 0);               \
    ACC = __builtin_amdgcn_mfma_f32_16x16x32_bf16(Ah0, L0, ACC, 0, 0, 0);               \
    ACC = __builtin_amdgcn_mfma_f32_16x16x32_bf16(Ah1, L1, ACC, 0, 0, 0);

__global__ __launch_bounds__(256, 2) void knn_kernel(
        const unsigned short* __restrict__ Xhi, const unsigned short* __restrict__ Xlo,
        const int* __restrict__ fps_idx, const float* __restrict__ xnorm,
        unsigned short* __restrict__ cand) {
    __shared__ float TL[4][16][32];            // [wave][q][col*2+{0,1}] collected values
    __shared__ float TQ[4][16];                // per-query threshold
    __shared__ int   cntL[4][16];
    __shared__ unsigned short buf[4][16][64];
    const int t = threadIdx.x, b = blockIdx.x;
    const int cloud = b & 15, qg = (b >> 4) & 15, half = b >> 8;
    const int wave = t >> 6, lane = t & 63;
    const int quad = lane >> 4, col = lane & 15;
    const int cbase = cloud * NP;
    const int qloc = qg * 64 + wave * 16;

    // A fragments (loop-invariant): A[m=lane&15][k=quad*8+j]
    const int qrow = fps_idx[cloud * MS + qloc + col];
    const unsigned short* Qh = Xhi + (size_t)(cbase + qrow) * 64;
    const unsigned short* Ql = Xlo + (size_t)(cbase + qrow) * 64;
    short8 Ah0 = *(const short8*)(Qh + quad * 8);
    short8 Ah1 = *(const short8*)(Qh + 32 + quad * 8);
    short8 Al0 = *(const short8*)(Ql + quad * 8);
    short8 Al1 = *(const short8*)(Ql + 32 + quad * 8);

    const int pstart = half * 2048;
    // -------- phase 1: unconditional 2-smallest per (lane, r) stream (depth-2 pipeline)
    float mA[4] = {INFINITY, INFINITY, INFINITY, INFINITY};
    float mB[4] = {INFINITY, INFINITY, INFINITY, INFINITY};
    {
        short8 ah0, ah1, al0, al1; float axn;   // slot A (even tiles)
        short8 bh0, bh1, bl0, bl1; float bxn;   // slot B (odd tiles)
        KNN_LOAD(ah0, ah1, al0, al1, axn, 0)
        KNN_LOAD(bh0, bh1, bl0, bl1, bxn, 1)
        for (int tt = 0; tt < 128; tt += 2) {
            // even tile tt: consume slot A, refill from tt+2
            {
                f32x4 acc = {0.f, 0.f, 0.f, 0.f};
                KNN_MFMA(acc, ah0, ah1, al0, al1)
                float xnv = axn;
                if (tt + 2 < 128) KNN_LOAD(ah0, ah1, al0, al1, axn, tt + 2)
#pragma unroll
                for (int r = 0; r < 4; r++) {
                    float s = fmaf(-2.0f, acc[r], xnv);
                    float mx = fmaxf(mA[r], s);
                    mA[r] = fminf(mA[r], s);
                    mB[r] = fminf(mB[r], mx);
                }
            }
            // odd tile tt+1: consume slot B, refill from tt+3
            {
                f32x4 acc = {0.f, 0.f, 0.f, 0.f};
                KNN_MFMA(acc, bh0, bh1, bl0, bl1)
                float xnv = bxn;
                if (tt + 3 < 128) KNN_LOAD(bh0, bh1, bl0, bl1, bxn, tt + 3)
#pragma unroll
                for (int r = 0; r < 4; r++) {
                    float s = fmaf(-2.0f, acc[r], xnv);
                    float mx = fmaxf(mA[r], s);
                    mA[r] = fminf(mA[r], s);
                    mB[r] = fminf(mB[r], mx);
                }
            }
        }
    }
    // -------- threshold: T[q] = 16th smallest of {mA,mB over 16 cols} (wave-local LDS, no barrier)
#pragma unroll
    for (int r = 0; r < 4; r++) {
        TL[wave][quad * 4 + r][col * 2 + 0] = mA[r];
        TL[wave][quad * 4 + r][col * 2 + 1] = mB[r];
    }
    if (lane < 16) cntL[wave][lane] = 0;
    {
        const int q = lane >> 2, j0 = (lane & 3) * 8;
        float v[32];
#pragma unroll
        for (int j = 0; j < 32; j++) v[j] = TL[wave][q][j];
#pragma unroll
        for (int u = 0; u < 8; u++) {
            float vj = TL[wave][q][j0 + u];
            int jj = j0 + u, rank = 0;
#pragma unroll
            for (int k = 0; k < 32; k++)
                rank += (v[k] < vj || (v[k] == vj && k < jj)) ? 1 : 0;
            if (rank == 15) TQ[wave][q] = vj;
        }
    }
    // -------- phase 2: emit candidates below threshold (depth-2 pipeline)
    float T0 = TQ[wave][quad * 4 + 0] + KNN_MARGIN;
    float T1 = TQ[wave][quad * 4 + 1] + KNN_MARGIN;
    float T2 = TQ[wave][quad * 4 + 2] + KNN_MARGIN;
    float T3 = TQ[wave][quad * 4 + 3] + KNN_MARGIN;
    {
        short8 ah0, ah1, al0, al1; float axn;
        short8 bh0, bh1, bl0, bl1; float bxn;
        KNN_LOAD(ah0, ah1, al0, al1, axn, 0)
        KNN_LOAD(bh0, bh1, bl0, bl1, bxn, 1)
        for (int tt = 0; tt < 128; tt += 2) {
            {
                f32x4 acc = {0.f, 0.f, 0.f, 0.f};
                KNN_MFMA(acc, ah0, ah1, al0, al1)
                float xnv = axn;
                if (tt + 2 < 128) KNN_LOAD(ah0, ah1, al0, al1, axn, tt + 2)
                const int pidx = pstart + tt * 16 + col;
                float s0 = fmaf(-2.0f, acc[0], xnv);
                float s1 = fmaf(-2.0f, acc[1], xnv);
                float s2 = fmaf(-2.0f, acc[2], xnv);
                float s3 = fmaf(-2.0f, acc[3], xnv);
                if (s0 <= T0) { int p = atomicAdd(&cntL[wave][quad * 4 + 0], 1); if (p < 64) buf[wave][quad * 4 + 0][p] = (unsigned short)pidx; }
                if (s1 <= T1) { int p = atomicAdd(&cntL[wave][quad * 4 + 1], 1); if (p < 64) buf[wave][quad * 4 + 1][p] = (unsigned short)pidx; }
                if (s2 <= T2) { int p = atomicAdd(&cntL[wave][quad * 4 + 2], 1); if (p < 64) buf[wave][quad * 4 + 2][p] = (unsigned short)pidx; }
                if (s3 <= T3) { int p = atomicAdd(&cntL[wave][quad * 4 + 3], 1); if (p < 64) buf[wave][quad * 4 + 3][p] = (unsigned short)pidx; }
            }
            {
                f32x4 acc = {0.f, 0.f, 0.f, 0.f};
                KNN_MFMA(acc, bh0, bh1, bl0, bl1)
                float xnv = bxn;
                if (tt + 3 < 128) KNN_LOAD(bh0, bh1, bl0, bl1, bxn, tt + 3)
                const int pidx = pstart + (tt + 1) * 16 + col;
                float s0 = fmaf(-2.0f, acc[0], xnv);
                float s1 = fmaf(-2.0f, acc[1], xnv);
                float s2 = fmaf(-2.0f, acc[2], xnv);
                float s3 = fmaf(-2.0f, acc[3], xnv);
                if (s0 <= T0) { int p = atomicAdd(&cntL[wave][quad * 4 + 0], 1); if (p < 64) buf[wave][quad * 4 + 0][p] = (unsigned short)pidx; }
                if (s1 <= T1) { int p = atomicAdd(&cntL[wave][quad * 4 + 1], 1); if (p < 64) buf[wave][quad * 4 + 1][p] = (unsigned short)pidx; }
                if (s2 <= T2) { int p = atomicAdd(&cntL[wave][quad * 4 + 2], 1); if (p < 64) buf[wave][quad * 4 + 2][p] = (unsigned short)pidx; }
                if (s3 <= T3) { int p = atomicAdd(&cntL[wave][quad * 4 + 3], 1); if (p < 64) buf[wave][quad * 4 + 3][p] = (unsigned short)pidx; }
            }
        }
    }
    // -------- dump (coalesced 128B per query; sentinel-pad)
#pragma unroll
    for (int q = 0; q < 16; q++) {
        int n = cntL[wave][q];
        unsigned short val = (lane < n) ? buf[wave][q][lane] : (unsigned short)0xFFFF;
        cand[(size_t)(cloud * MS + qloc + q) * 128 + half * 64 + lane] = val;
    }
}

// ---------------------------------------------------------------- refine: exact fp32 top-16 + gather/BN/ReLU/maxpool
// block = one query; 128 candidate slots (sentinel-padded), 2 lanes/candidate.
__global__ __launch_bounds__(256) void refine_kernel(
        const float* __restrict__ feat, const int* __restrict__ fps_idx,
        const float* __restrict__ xnorm, const unsigned short* __restrict__ cand,
        const __hip_bfloat16* __restrict__ h, const float* __restrict__ acoef,
        const float* __restrict__ ccoef, float* __restrict__ out_feat) {
    __shared__ float qlds[64];
    __shared__ float cD[128];
    __shared__ int   cI[128];
    __shared__ int   fIdx[16];
    __shared__ float cf[256];
    const int t = threadIdx.x, b = blockIdx.x;
    const int cloud = b & 15, m = b >> 4;          // cloud <-> XCD locality
    const int q = cloud * MS + m;
    const int cbase = cloud * NP;
    if (t < 128) cf[t] = acoef[t]; else cf[t] = ccoef[t - 128];
    if (t < 16) {
        int qr = fps_idx[q];
        float4 v = ((const float4*)(feat + (size_t)(cbase + qr) * FIN))[t];
        *(float4*)&qlds[t * 4] = v;
    }
    __syncthreads();
    // exact fp32 distance: candidate c = t>>1, half jh = t&1 covers 32 dims
    const int c = t >> 1, jh = t & 1;
    const unsigned short cs = cand[(size_t)q * 128 + c];
    const bool valid = (cs != 0xFFFF);
    const int cidx = valid ? (int)cs : 0;
    const float4* xr = (const float4*)(feat + (size_t)(cbase + cidx) * FIN) + jh * 8;
    float a0 = 0.f, a1 = 0.f, a2 = 0.f, a3 = 0.f;
#pragma unroll
    for (int i = 0; i < 8; i++) {
        float4 x4 = xr[i];
        a0 = fmaf(qlds[jh * 32 + 4 * i + 0], x4.x, a0);
        a1 = fmaf(qlds[jh * 32 + 4 * i + 1], x4.y, a1);
        a2 = fmaf(qlds[jh * 32 + 4 * i + 2], x4.z, a2);
        a3 = fmaf(qlds[jh * 32 + 4 * i + 3], x4.w, a3);
    }
    float a = (a0 + a1) + (a2 + a3);
    a += __shfl_xor(a, 1);
    if (jh == 0) {
        cD[c] = valid ? fmaf(-2.0f, a, xnorm[cbase + cidx]) : INFINITY;
        cI[c] = valid ? cidx : (65536 + c);   // distinct tiebreak ids for sentinels
    }
    __syncthreads();
    // rank-count among 128 (lex (d, idx); >=32 real distinct candidates guaranteed)
    if (t < 128) {
        float dv = cD[t]; int iv = cI[t]; int rank = 0;
#pragma unroll 8
        for (int j = 0; j < 128; j++) {
            float dj = cD[j]; int ij = cI[j];
            rank += (dj < dv || (dj == dv && ij < iv)) ? 1 : 0;
        }
        if (rank < 16) fIdx[rank] = iv;
    }
    __syncthreads();
    // gather + BN affine + relu + maxpool
    if (t < 128) {
        const __hip_bfloat16* hb = h + (size_t)cbase * FOUT;
        const float ac = cf[t], cc = cf[128 + t];
        float mx = -INFINITY;
#pragma unroll
        for (int k = 0; k < 16; k++) {
            int row = fIdx[k];
            float hv = __bfloat162float(hb[(size_t)row * FOUT + t]);
            mx = fmaxf(mx, fmaxf(fmaf(ac, hv, cc), 0.f));
        }
        out_feat[(size_t)q * FOUT + t] = mx;
    }
}

// ---------------------------------------------------------------- launch
extern "C" void kernel_launch(void* const* d_in, const int* in_sizes, int n_in,
                              void* d_out, int out_size, void* d_ws, size_t ws_size,
                              hipStream_t stream) {
    (void)in_sizes; (void)n_in; (void)out_size; (void)ws_size;
    const float* position = (const float*)d_in[0];
    const float* features = (const float*)d_in[1];
    const float* W        = (const float*)d_in[3];
    const float* bias     = (const float*)d_in[4];
    const float* gamma    = (const float*)d_in[5];
    const float* beta     = (const float*)d_in[6];
    float* out = (float*)d_out;

    char* ws = (char*)d_ws;
    int*   fps_idx = (int*)ws;                               // 64 KB
    float* gsum    = (float*)(ws + 65536);                   // 512 B
    float* gsq     = (float*)(ws + 66048);                   // 512 B
    float* acoef   = (float*)(ws + 66560);                   // 512 B
    float* ccoef   = (float*)(ws + 67072);                   // 512 B
    float* xnorm   = (float*)(ws + 67584);                   // 256 KB -> ends 329728
    unsigned short* cand = (unsigned short*)(ws + 329728);   // 4 MB   -> ends 4524032
    unsigned short* Xhi  = (unsigned short*)(ws + 4524032);  // 8 MB   -> ends 12912640
    __hip_bfloat16* hbuf = (__hip_bfloat16*)(ws + 12912640); // 16 MB  -> ends ~29.7 MB

    float* out_feat  = out;                 // [16384][128]
    float* out_pos   = out + 2097152;       // [16384][3]
    float* out_batch = out + 2146304;       // [16384]
    // Stash Xlo in the out_feat region (8 MB exact fit); refine overwrites it afterwards.
    unsigned short* Xlo = (unsigned short*)out;

    hipMemsetAsync(gsum, 0, 1024, stream);  // zero gsum+gsq
    front_kernel<<<400, 512, 0, stream>>>(position, features, W, bias,
                                          fps_idx, out_pos, out_batch, xnorm, Xhi, Xlo,
                                          hbuf, gsum, gsq);
    finalize_kernel<<<1, FOUT, 0, stream>>>(gsum, gsq, gamma, beta, acoef, ccoef);
    knn_kernel<<<512, 256, 0, stream>>>(Xhi, Xlo, fps_idx, xnorm, cand);
    refine_kernel<<<16384, 256, 0, stream>>>(features, fps_idx, xnorm, cand,
                                             hbuf, acoef, ccoef, out_feat);
}

// Round 9
// 949.249 us; speedup vs baseline: 1.1386x; 1.0087x over previous
//
#include <hip/hip_runtime.h>
#include <hip/hip_bf16.h>

#define NB 16
#define NP 4096
#define MS 1024
#define NN 65536
#define FIN 64
#define FOUT 128
#define KNN_MARGIN 0.25f

typedef __attribute__((ext_vector_type(8))) short short8;
typedef __attribute__((ext_vector_type(4))) float f32x4;
typedef __attribute__((ext_vector_type(2))) float f32x2;

// DPP cumulative-max step on a (dist,idx) key, using v_max_f64.
// Keys are positive f64 bit patterns (finite f32 dist in high word => never NaN),
// so IEEE fmax == unsigned 64-bit max. Invalid DPP lanes -> 0.0 (identity).
template <int CTRL>
__device__ __forceinline__ unsigned long long dpp_fmax_step(unsigned long long k) {
    unsigned lo = (unsigned)k, hi = (unsigned)(k >> 32);
    unsigned plo = (unsigned)__builtin_amdgcn_update_dpp(0, (int)lo, CTRL, 0xf, 0xf, true);
    unsigned phi = (unsigned)__builtin_amdgcn_update_dpp(0, (int)hi, CTRL, 0xf, 0xf, true);
    unsigned long long pk = ((unsigned long long)phi << 32) | plo;
    double a = __builtin_bit_cast(double, k);
    double p = __builtin_bit_cast(double, pk);
    return __builtin_bit_cast(unsigned long long, fmax(a, p));
}

__device__ __forceinline__ unsigned short bf16_rn(float v) {
    unsigned u = __float_as_uint(v);
    unsigned r = u + 0x7FFF + ((u >> 16) & 1);
    return (unsigned short)(r >> 16);
}

// ---------------------------------------------------------------- front: FPS + GEMM + xnorm/split fused
__global__ __launch_bounds__(512, 1) void front_kernel(
        const float* __restrict__ pos, const float* __restrict__ feat,
        const float* __restrict__ W, const float* __restrict__ bias,
        int* __restrict__ fps_idx, float* __restrict__ out_pos, float* __restrict__ out_batch,
        float* __restrict__ xnorm, unsigned short* __restrict__ Xhi, unsigned short* __restrict__ Xlo,
        __hip_bfloat16* __restrict__ hout, float* __restrict__ gsum, float* __restrict__ gsq) {
    // FPS view: plds4[4096] float4 (65536 B) + idxL[1024] int (4096 B) + wk[2][8] double (128 B)
    // GEMM view: first 52224 B as floats (wt/fl)
    __shared__ __align__(16) char smraw[69760];
    const int t = threadIdx.x;
    const int b = blockIdx.x;
    if (b < 16) {
        // ---------------- FPS: 512 threads x 8 pts/thread (4 x f32x2 packed pairs)
        // Dist update uses packed FP32 (v_pk_fma/pk_min); combine = R2-proven flat
        // broadcast tree with keys read as double2 (b128 pairs).
        float4* plds4 = (float4*)smraw;
        float*  plin  = (float*)smraw;                    // linear staging view
        int* idxL = (int*)(smraw + 65536);
        double* wk = (double*)(smraw + 65536 + 4096);     // [2][8] per-wave keys (16B aligned)
        const float* pb = pos + (size_t)b * NP * 3;
#pragma unroll
        for (int i = 0; i < 24; i++) { int id = t + 512 * i; plin[id] = pb[id]; }
        __syncthreads();
        f32x2 px2[4], py2[4], pz2[4], dist2[4];
#pragma unroll
        for (int j = 0; j < 4; j++) {
            int p0 = t + 512 * (2 * j), p1 = p0 + 512;
            px2[j] = {plin[p0 * 3 + 0], plin[p1 * 3 + 0]};
            py2[j] = {plin[p0 * 3 + 1], plin[p1 * 3 + 1]};
            pz2[j] = {plin[p0 * 3 + 2], plin[p1 * 3 + 2]};
            dist2[j] = {INFINITY, INFINITY};
        }
        __syncthreads();   // all linear reads done before float4 overwrite
#pragma unroll
        for (int j = 0; j < 4; j++) {
            plds4[t + 512 * (2 * j)]     = (float4){px2[j][0], py2[j][0], pz2[j][0], 0.f};
            plds4[t + 512 * (2 * j + 1)] = (float4){px2[j][1], py2[j][1], pz2[j][1], 0.f};
        }
        if (t == 0) idxL[0] = 0;
        __syncthreads();
        float4 c0 = plds4[0];
        float lx = c0.x, ly = c0.y, lz = c0.z;
        const int ln = t & 63, wv = t >> 6;   // 8 waves
        for (int m = 1; m < MS; m++) {
#pragma unroll
            for (int j = 0; j < 4; j++) {
                f32x2 dx = px2[j] - lx, dy = py2[j] - ly, dz = pz2[j] - lz;
                f32x2 d = dx * dx + dy * dy + dz * dz;
                dist2[j] = __builtin_elementwise_min(dist2[j], d);
            }
            // local argmax tree over the 8 packed dists (i ordering = point t+512*i)
            float d1[4]; int i1[4];
#pragma unroll
            for (int j = 0; j < 4; j++) {
                bool g = dist2[j][1] > dist2[j][0];
                d1[j] = g ? dist2[j][1] : dist2[j][0];
                i1[j] = 2 * j + (g ? 1 : 0);
            }
            float d2[2]; int i2[2];
#pragma unroll
            for (int j = 0; j < 2; j++) {
                bool g = d1[j + 2] > d1[j];
                d2[j] = g ? d1[j + 2] : d1[j]; i2[j] = g ? i1[j + 2] : i1[j];
            }
            bool g3 = d2[1] > d2[0];
            float bd = g3 ? d2[1] : d2[0];
            int bi = g3 ? i2[1] : i2[0];
            int bp = t + (bi << 9);
            unsigned long long key =
                ((unsigned long long)__float_as_uint(bd) << 32) | (unsigned)(~bp);
            key = dpp_fmax_step<0x111>(key);   // row_shr:1
            key = dpp_fmax_step<0x112>(key);   // row_shr:2
            key = dpp_fmax_step<0x114>(key);   // row_shr:4
            key = dpp_fmax_step<0x118>(key);   // row_shr:8
            key = dpp_fmax_step<0x142>(key);   // row_bcast15
            key = dpp_fmax_step<0x143>(key);   // row_bcast31
            const int par = (m & 1) * 8;
            if (ln == 63) wk[par + wv] = __builtin_bit_cast(double, key);
            __syncthreads();
            const double2* wk2 = (const double2*)(wk + par);   // 4 x b128 broadcast reads
            double2 q01 = wk2[0], q23 = wk2[1], q45 = wk2[2], q67 = wk2[3];
            double ka = fmax(q01.x, q01.y), kb = fmax(q23.x, q23.y);
            double kc = fmax(q45.x, q45.y), kd = fmax(q67.x, q67.y);
            ka = fmax(ka, kb);
            kc = fmax(kc, kd);
            unsigned long long kw = __builtin_bit_cast(unsigned long long, fmax(ka, kc));
            bp = (int)(~(unsigned)kw) & 0xFFF;
            float4 c = plds4[bp];                          // one b128 coords read
            lx = c.x; ly = c.y; lz = c.z;
            if (t == 0) idxL[m] = bp;
        }
        __syncthreads();
        for (int m = t; m < MS; m += 512) {
            int ix = idxL[m];
            size_t o = (size_t)b * MS + m;
            fps_idx[o] = ix;
            float4 c = plds4[ix];
            out_pos[o * 3 + 0] = c.x;
            out_pos[o * 3 + 1] = c.y;
            out_pos[o * 3 + 2] = c.z;
            out_batch[o] = (float)b;
        }
    } else if (b < 272) {
        // ---------------- GEMM + BN stats (rows (b-16)*256 .. +255), 512 threads
        float* wt = (float*)smraw;            // [128][68] W^T
        float* fl = (float*)smraw + 8704;     // [64][68] feature tile
#pragma unroll
        for (int it = 0; it < 4; it++) {
            int lid = t + 512 * it;
            int k = lid >> 5, c4 = lid & 31;
            float4 v = *(const float4*)&W[k * FOUT + c4 * 4];
            wt[(c4 * 4 + 0) * 68 + k] = v.x;
            wt[(c4 * 4 + 1) * 68 + k] = v.y;
            wt[(c4 * 4 + 2) * 68 + k] = v.z;
            wt[(c4 * 4 + 3) * 68 + k] = v.w;
        }
        const int rowbase0 = (b - 16) * 256;
        const int rg = t >> 5, cg = t & 31;
        float sums[4] = {0, 0, 0, 0};
        float sqs[4]  = {0, 0, 0, 0};
        for (int sub = 0; sub < 4; sub++) {
            const int rowbase = rowbase0 + sub * 64;
            __syncthreads();
#pragma unroll
            for (int it = 0; it < 2; it++) {
                int lid = t + 512 * it;
                int r = lid >> 4, f4 = lid & 15;
                float4 v = *(const float4*)&feat[(size_t)(rowbase + r) * FIN + f4 * 4];
                *(float4*)&fl[r * 68 + f4 * 4] = v;
            }
            __syncthreads();
            float acc[4][4];
#pragma unroll
            for (int i = 0; i < 4; i++)
#pragma unroll
                for (int j = 0; j < 4; j++) acc[i][j] = 0.f;
#pragma unroll 2
            for (int k4 = 0; k4 < 16; k4++) {
                float4 f4v[4], w4v[4];
#pragma unroll
                for (int i = 0; i < 4; i++) f4v[i] = *(float4*)&fl[(rg * 4 + i) * 68 + k4 * 4];
#pragma unroll
                for (int j = 0; j < 4; j++) w4v[j] = *(float4*)&wt[(cg + 32 * j) * 68 + k4 * 4];
#pragma unroll
                for (int i = 0; i < 4; i++)
#pragma unroll
                    for (int j = 0; j < 4; j++) {
                        acc[i][j] = fmaf(f4v[i].x, w4v[j].x, acc[i][j]);
                        acc[i][j] = fmaf(f4v[i].y, w4v[j].y, acc[i][j]);
                        acc[i][j] = fmaf(f4v[i].z, w4v[j].z, acc[i][j]);
                        acc[i][j] = fmaf(f4v[i].w, w4v[j].w, acc[i][j]);
                    }
            }
#pragma unroll
            for (int j = 0; j < 4; j++) {
                int c = cg + 32 * j;
                float bc = bias[c];
#pragma unroll
                for (int i = 0; i < 4; i++) {
                    float h = acc[i][j] + bc;
                    sums[j] += h; sqs[j] += h * h;
                    hout[(size_t)(rowbase + rg * 4 + i) * FOUT + c] = __float2bfloat16(h);
                }
            }
        }
        __syncthreads();
        float* suml = fl;
        float* sql  = wt;
#pragma unroll
        for (int j = 0; j < 4; j++) {
            suml[rg * FOUT + cg + 32 * j] = sums[j];
            sql[rg * FOUT + cg + 32 * j]  = sqs[j];
        }
        __syncthreads();
        if (t < FOUT) {
            float S = 0.f, Q = 0.f;
#pragma unroll
            for (int r = 0; r < 16; r++) { S += suml[r * FOUT + t]; Q += sql[r * FOUT + t]; }
            atomicAdd(&gsum[t], S);
            atomicAdd(&gsq[t], Q);
        }
    } else {
        // ---------------- xnorm + bf16 hi/lo split (512 threads, 128 blocks)
        int r = (b - 272) * 512 + t;
        const float4* fr = (const float4*)&feat[(size_t)r * FIN];
        unsigned short hrow[64], lrow[64];
        float s = 0.f;
#pragma unroll
        for (int i = 0; i < 16; i++) {
            float4 v = fr[i];
            s += v.x * v.x + v.y * v.y + v.z * v.z + v.w * v.w;
            float vv[4] = {v.x, v.y, v.z, v.w};
#pragma unroll
            for (int j = 0; j < 4; j++) {
                unsigned short h = bf16_rn(vv[j]);
                float hf = __uint_as_float((unsigned)h << 16);
                hrow[4 * i + j] = h;
                lrow[4 * i + j] = bf16_rn(vv[j] - hf);
            }
        }
        xnorm[r] = s;
#pragma unroll
        for (int i = 0; i < 8; i++) {
            short8 hv, lv;
#pragma unroll
            for (int j = 0; j < 8; j++) { hv[j] = (short)hrow[8 * i + j]; lv[j] = (short)lrow[8 * i + j]; }
            *(short8*)&Xhi[(size_t)r * 64 + 8 * i] = hv;
            *(short8*)&Xlo[(size_t)r * 64 + 8 * i] = lv;
        }
    }
}

// ---------------------------------------------------------------- KNN filter: MFMA + two-phase threshold
// grid 512: cloud(16) x qgroup(16) x half(2). Wave w owns queries qg*64+w*16..+15 vs 2048 points.
// Depth-2 software pipeline (manual unroll-by-2, two named register slots).
#define KNN_LOAD(SLOT_H0, SLOT_H1, SLOT_L0, SLOT_L1, SLOT_XN, TILE)                     \
    {                                                                                   \
        const int pr_ = cbase + pstart + (TILE) * 16 + col;                             \
        const unsigned short* Bh_ = Xhi + (size_t)pr_ * 64;                             \
        const unsigned short* Bl_ = Xlo + (size_t)pr_ * 64;                             \
        SLOT_H0 = *(const short8*)(Bh_ + quad * 8);                                     \
        SLOT_H1 = *(const short8*)(Bh_ + 32 + quad * 8);                                \
        SLOT_L0 = *(const short8*)(Bl_ + quad * 8);                                     \
        SLOT_L1 = *(const short8*)(Bl_ + 32 + quad * 8);                                \
        SLOT_XN = xnorm[pr_];                                                           \
    }

#define KNN_MFMA(ACC, H0, H1, L0, L1)                                                   \
    ACC = __builtin_amdgcn_mfma_f32_16x16x32_bf16(Ah0, H0, ACC, 0, 0, 0);               \
    ACC = __builtin_amdgcn_mfma_f32_16x16x32_bf16(Ah1, H1, ACC, 0, 0, 0);               \
    ACC = __builtin_amdgcn_mfma_f32_16x16x32_bf16(Al0, H0, ACC, 0, 0, 0);               \
    ACC = __builtin_amdgcn_mfma_f32_16x16x32_bf16(Al1, H1, ACC, 0, 0, 0);               \
    ACC = __builtin_amdgcn_mfma_f32_16x16x32_bf16(Ah0, L0, ACC, 0, 0, 0);               \
    ACC = __builtin_amdgcn_mfma_f32_16x16x32_bf16(Ah1, L1, ACC, 0, 0, 0);

__global__ __launch_bounds__(256, 2) void knn_kernel(
        const unsigned short* __restrict__ Xhi, const unsigned short* __restrict__ Xlo,
        const int* __restrict__ fps_idx, const float* __restrict__ xnorm,
        unsigned short* __restrict__ cand) {
    __shared__ float TL[4][16][32];            // [wave][q][col*2+{0,1}] collected values
    __shared__ float TQ[4][16];                // per-query threshold
    __shared__ int   cntL[4][16];
    __shared__ unsigned short buf[4][16][64];
    const int t = threadIdx.x, b = blockIdx.x;
    const int cloud = b & 15, qg = (b >> 4) & 15, half = b >> 8;
    const int wave = t >> 6, lane = t & 63;
    const int quad = lane >> 4, col = lane & 15;
    const int cbase = cloud * NP;
    const int qloc = qg * 64 + wave * 16;

    // A fragments (loop-invariant): A[m=lane&15][k=quad*8+j]
    const int qrow = fps_idx[cloud * MS + qloc + col];
    const unsigned short* Qh = Xhi + (size_t)(cbase + qrow) * 64;
    const unsigned short* Ql = Xlo + (size_t)(cbase + qrow) * 64;
    short8 Ah0 = *(const short8*)(Qh + quad * 8);
    short8 Ah1 = *(const short8*)(Qh + 32 + quad * 8);
    short8 Al0 = *(const short8*)(Ql + quad * 8);
    short8 Al1 = *(const short8*)(Ql + 32 + quad * 8);

    const int pstart = half * 2048;
    // -------- phase 1: unconditional 2-smallest per (lane, r) stream (depth-2 pipeline)
    float mA[4] = {INFINITY, INFINITY, INFINITY, INFINITY};
    float mB[4] = {INFINITY, INFINITY, INFINITY, INFINITY};
    {
        short8 ah0, ah1, al0, al1; float axn;   // slot A (even tiles)
        short8 bh0, bh1, bl0, bl1; float bxn;   // slot B (odd tiles)
        KNN_LOAD(ah0, ah1, al0, al1, axn, 0)
        KNN_LOAD(bh0, bh1, bl0, bl1, bxn, 1)
        for (int tt = 0; tt < 128; tt += 2) {
            // even tile tt: consume slot A, refill from tt+2
            {
                f32x4 acc = {0.f, 0.f, 0.f, 0.f};
                KNN_MFMA(acc, ah0, ah1, al0, al1)
                float xnv = axn;
                if (tt + 2 < 128) KNN_LOAD(ah0, ah1, al0, al1, axn, tt + 2)
#pragma unroll
                for (int r = 0; r < 4; r++) {
                    float s = fmaf(-2.0f, acc[r], xnv);
                    float mx = fmaxf(mA[r], s);
                    mA[r] = fminf(mA[r], s);
                    mB[r] = fminf(mB[r], mx);
                }
            }
            // odd tile tt+1: consume slot B, refill from tt+3
            {
                f32x4 acc = {0.f, 0.f, 0.f, 0.f};
                KNN_MFMA(acc, bh0, bh1, bl0, bl1)
                float xnv = bxn;
                if (tt + 3 < 128) KNN_LOAD(bh0, bh1, bl0, bl1, bxn, tt + 3)
#pragma unroll
                for (int r = 0; r < 4; r++) {
                    float s = fmaf(-2.0f, acc[r], xnv);
                    float mx = fmaxf(mA[r], s);
                    mA[r] = fminf(mA[r], s);
                    mB[r] = fminf(mB[r], mx);
                }
            }
        }
    }
    // -------- threshold: T[q] = 16th smallest of {mA,mB over 16 cols} (wave-local LDS, no barrier)
#pragma unroll
    for (int r = 0; r < 4; r++) {
        TL[wave][quad * 4 + r][col * 2 + 0] = mA[r];
        TL[wave][quad * 4 + r][col * 2 + 1] = mB[r];
    }
    if (lane < 16) cntL[wave][lane] = 0;
    {
        const int q = lane >> 2, j0 = (lane & 3) * 8;
        float v[32];
#pragma unroll
        for (int j = 0; j < 32; j++) v[j] = TL[wave][q][j];
#pragma unroll
        for (int u = 0; u < 8; u++) {
            float vj = TL[wave][q][j0 + u];
            int jj = j0 + u, rank = 0;
#pragma unroll
            for (int k = 0; k < 32; k++)
                rank += (v[k] < vj || (v[k] == vj && k < jj)) ? 1 : 0;
            if (rank == 15) TQ[wave][q] = vj;
        }
    }
    // -------- phase 2: emit candidates below threshold (depth-2 pipeline)
    float T0 = TQ[wave][quad * 4 + 0] + KNN_MARGIN;
    float T1 = TQ[wave][quad * 4 + 1] + KNN_MARGIN;
    float T2 = TQ[wave][quad * 4 + 2] + KNN_MARGIN;
    float T3 = TQ[wave][quad * 4 + 3] + KNN_MARGIN;
    {
        short8 ah0, ah1, al0, al1; float axn;
        short8 bh0, bh1, bl0, bl1; float bxn;
        KNN_LOAD(ah0, ah1, al0, al1, axn, 0)
        KNN_LOAD(bh0, bh1, bl0, bl1, bxn, 1)
        for (int tt = 0; tt < 128; tt += 2) {
            {
                f32x4 acc = {0.f, 0.f, 0.f, 0.f};
                KNN_MFMA(acc, ah0, ah1, al0, al1)
                float xnv = axn;
                if (tt + 2 < 128) KNN_LOAD(ah0, ah1, al0, al1, axn, tt + 2)
                const int pidx = pstart + tt * 16 + col;
                float s0 = fmaf(-2.0f, acc[0], xnv);
                float s1 = fmaf(-2.0f, acc[1], xnv);
                float s2 = fmaf(-2.0f, acc[2], xnv);
                float s3 = fmaf(-2.0f, acc[3], xnv);
                if (s0 <= T0) { int p = atomicAdd(&cntL[wave][quad * 4 + 0], 1); if (p < 64) buf[wave][quad * 4 + 0][p] = (unsigned short)pidx; }
                if (s1 <= T1) { int p = atomicAdd(&cntL[wave][quad * 4 + 1], 1); if (p < 64) buf[wave][quad * 4 + 1][p] = (unsigned short)pidx; }
                if (s2 <= T2) { int p = atomicAdd(&cntL[wave][quad * 4 + 2], 1); if (p < 64) buf[wave][quad * 4 + 2][p] = (unsigned short)pidx; }
                if (s3 <= T3) { int p = atomicAdd(&cntL[wave][quad * 4 + 3], 1); if (p < 64) buf[wave][quad * 4 + 3][p] = (unsigned short)pidx; }
            }
            {
                f32x4 acc = {0.f, 0.f, 0.f, 0.f};
                KNN_MFMA(acc, bh0, bh1, bl0, bl1)
                float xnv = bxn;
                if (tt + 3 < 128) KNN_LOAD(bh0, bh1, bl0, bl1, bxn, tt + 3)
                const int pidx = pstart + (tt + 1) * 16 + col;
                float s0 = fmaf(-2.0f, acc[0], xnv);
                float s1 = fmaf(-2.0f, acc[1], xnv);
                float s2 = fmaf(-2.0f, acc[2], xnv);
                float s3 = fmaf(-2.0f, acc[3], xnv);
                if (s0 <= T0) { int p = atomicAdd(&cntL[wave][quad * 4 + 0], 1); if (p < 64) buf[wave][quad * 4 + 0][p] = (unsigned short)pidx; }
                if (s1 <= T1) { int p = atomicAdd(&cntL[wave][quad * 4 + 1], 1); if (p < 64) buf[wave][quad * 4 + 1][p] = (unsigned short)pidx; }
                if (s2 <= T2) { int p = atomicAdd(&cntL[wave][quad * 4 + 2], 1); if (p < 64) buf[wave][quad * 4 + 2][p] = (unsigned short)pidx; }
                if (s3 <= T3) { int p = atomicAdd(&cntL[wave][quad * 4 + 3], 1); if (p < 64) buf[wave][quad * 4 + 3][p] = (unsigned short)pidx; }
            }
        }
    }
    // -------- dump (coalesced 128B per query; sentinel-pad)
#pragma unroll
    for (int q = 0; q < 16; q++) {
        int n = cntL[wave][q];
        unsigned short val = (lane < n) ? buf[wave][q][lane] : (unsigned short)0xFFFF;
        cand[(size_t)(cloud * MS + qloc + q) * 128 + half * 64 + lane] = val;
    }
}

// ---------------------------------------------------------------- refine: exact fp32 top-16 + gather/BN/ReLU/maxpool
// block = one query; 128 candidate slots (sentinel-padded), 2 lanes/candidate.
// v2: (a) BN coefs computed inline from gsum/gsq (finalize kernel eliminated);
//     (b) rank-count reads packed (d,idx) pairs as int4 (4x fewer DS instrs) and
//         splits the j-scan across both thread halves (2x shorter);
//     (c) 16-row gather/maxpool split across halves (fmax-combine, bit-identical).
__global__ __launch_bounds__(256) void refine_kernel(
        const float* __restrict__ feat, const int* __restrict__ fps_idx,
        const float* __restrict__ xnorm, const unsigned short* __restrict__ cand,
        const __hip_bfloat16* __restrict__ h,
        const float* __restrict__ gsum, const float* __restrict__ gsq,
        const float* __restrict__ gamma, const float* __restrict__ beta,
        float* __restrict__ out_feat) {
    __shared__ float qlds[64];
    __shared__ __align__(16) int2 cDI[128];   // (float bits of d, idx) per candidate
    __shared__ int   rankH[128];
    __shared__ int   fIdx[16];
    __shared__ float cf[256];
    __shared__ float pmax[128];
    const int t = threadIdx.x, b = blockIdx.x;
    const int cloud = b & 15, m = b >> 4;          // cloud <-> XCD locality
    const int q = cloud * MS + m;
    const int cbase = cloud * NP;
    // BN coefs inline (same fp32 ops as old finalize -> bit-identical)
    if (t < 128) {
        float mean = gsum[t] * (1.0f / NN);
        float var  = gsq[t] * (1.0f / NN) - mean * mean;
        float s = rsqrtf(var + 1e-5f) * gamma[t];
        cf[t] = s;
        cf[128 + t] = beta[t] - mean * s;
    }
    if (t < 16) {
        int qr = fps_idx[q];
        float4 v = ((const float4*)(feat + (size_t)(cbase + qr) * FIN))[t];
        *(float4*)&qlds[t * 4] = v;
    }
    __syncthreads();
    // exact fp32 distance: candidate c = t>>1, half jh = t&1 covers 32 dims
    const int c = t >> 1, jh = t & 1;
    const unsigned short cs = cand[(size_t)q * 128 + c];
    const bool valid = (cs != 0xFFFF);
    const int cidx = valid ? (int)cs : 0;
    const float4* xr = (const float4*)(feat + (size_t)(cbase + cidx) * FIN) + jh * 8;
    float a0 = 0.f, a1 = 0.f, a2 = 0.f, a3 = 0.f;
#pragma unroll
    for (int i = 0; i < 8; i++) {
        float4 x4 = xr[i];
        a0 = fmaf(qlds[jh * 32 + 4 * i + 0], x4.x, a0);
        a1 = fmaf(qlds[jh * 32 + 4 * i + 1], x4.y, a1);
        a2 = fmaf(qlds[jh * 32 + 4 * i + 2], x4.z, a2);
        a3 = fmaf(qlds[jh * 32 + 4 * i + 3], x4.w, a3);
    }
    float a = (a0 + a1) + (a2 + a3);
    a += __shfl_xor(a, 1);
    if (jh == 0) {
        float dv = valid ? fmaf(-2.0f, a, xnorm[cbase + cidx]) : INFINITY;
        int   iv = valid ? cidx : (65536 + c);   // distinct tiebreak ids for sentinels
        cDI[c] = make_int2(__float_as_int(dv), iv);
    }
    __syncthreads();
    // rank-count among 128 (lex (d, idx)); thread t: candidate t&127, j-half t>>7
    {
        const int c2 = t & 127, jH = t >> 7;
        int2 my = cDI[c2];
        float dv = __int_as_float(my.x);
        int   iv = my.y;
        const int4* cDI4 = (const int4*)cDI;     // 2 candidates per read
        int rank = 0;
        const int base = jH * 32;                // 64 j's = 32 int4 reads
#pragma unroll 8
        for (int k2 = 0; k2 < 32; k2++) {
            int4 p = cDI4[base + k2];
            float d0 = __int_as_float(p.x); int i0 = p.y;
            float d1 = __int_as_float(p.z); int i1 = p.w;
            rank += (d0 < dv || (d0 == dv && i0 < iv)) ? 1 : 0;
            rank += (d1 < dv || (d1 == dv && i1 < iv)) ? 1 : 0;
        }
        if (jH) rankH[c2] = rank;
        __syncthreads();
        if (!jH) {
            rank += rankH[c2];
            if (rank < 16) fIdx[rank] = iv;
        }
    }
    __syncthreads();
    // gather + BN affine + relu + maxpool; k-halves split across thread halves
    {
        const int tc = t & 127, kH = t >> 7;
        const __hip_bfloat16* hb = h + (size_t)cbase * FOUT;
        const float ac = cf[tc], cc = cf[128 + tc];
        float mx = -INFINITY;
#pragma unroll
        for (int k = 0; k < 8; k++) {
            int row = fIdx[kH * 8 + k];
            float hv = __bfloat162float(hb[(size_t)row * FOUT + tc]);
            mx = fmaxf(mx, fmaxf(fmaf(ac, hv, cc), 0.f));
        }
        if (kH) pmax[tc] = mx;
        __syncthreads();
        if (!kH) out_feat[(size_t)q * FOUT + tc] = fmaxf(mx, pmax[tc]);
    }
}

// ---------------------------------------------------------------- launch
extern "C" void kernel_launch(void* const* d_in, const int* in_sizes, int n_in,
                              void* d_out, int out_size, void* d_ws, size_t ws_size,
                              hipStream_t stream) {
    (void)in_sizes; (void)n_in; (void)out_size; (void)ws_size;
    const float* position = (const float*)d_in[0];
    const float* features = (const float*)d_in[1];
    const float* W        = (const float*)d_in[3];
    const float* bias     = (const float*)d_in[4];
    const float* gamma    = (const float*)d_in[5];
    const float* beta     = (const float*)d_in[6];
    float* out = (float*)d_out;

    char* ws = (char*)d_ws;
    int*   fps_idx = (int*)ws;                               // 64 KB
    float* gsum    = (float*)(ws + 65536);                   // 512 B
    float* gsq     = (float*)(ws + 66048);                   // 512 B
    float* xnorm   = (float*)(ws + 67584);                   // 256 KB -> ends 329728
    unsigned short* cand = (unsigned short*)(ws + 329728);   // 4 MB   -> ends 4524032
    unsigned short* Xhi  = (unsigned short*)(ws + 4524032);  // 8 MB   -> ends 12912640
    __hip_bfloat16* hbuf = (__hip_bfloat16*)(ws + 12912640); // 16 MB  -> ends ~29.7 MB

    float* out_feat  = out;                 // [16384][128]
    float* out_pos   = out + 2097152;       // [16384][3]
    float* out_batch = out + 2146304;       // [16384]
    // Stash Xlo in the out_feat region (8 MB exact fit); refine overwrites it afterwards.
    unsigned short* Xlo = (unsigned short*)out;

    hipMemsetAsync(gsum, 0, 1024, stream);  // zero gsum+gsq
    front_kernel<<<400, 512, 0, stream>>>(position, features, W, bias,
                                          fps_idx, out_pos, out_batch, xnorm, Xhi, Xlo,
                                          hbuf, gsum, gsq);
    knn_kernel<<<512, 256, 0, stream>>>(Xhi, Xlo, fps_idx, xnorm, cand);
    refine_kernel<<<16384, 256, 0, stream>>>(features, fps_idx, xnorm, cand,
                                             hbuf, gsum, gsq, gamma, beta, out_feat);
}